// Round 7
// baseline (258.839 us; speedup 1.0000x reference)
//
#include <hip/hip_runtime.h>
#include <hip/hip_bf16.h>

#define B_ 4
#define T_ 2048
#define C_ 1024
#define H_ 16
#define D_ 64

typedef __attribute__((ext_vector_type(8))) short short8;
typedef __attribute__((ext_vector_type(4))) float f32x4;

// q pre-scale: (1/sqrt(D)) * log2(e) so attn uses raw v_exp_f32 (exp2)
#define QSCALE 0.18033688011112042f

static __device__ __forceinline__ unsigned short f2bf(float f) {
  unsigned u = __float_as_uint(f);
  u += 0x7fff + ((u >> 16) & 1);  // round-to-nearest-even
  return (unsigned short)(u >> 16);
}

// packed bf16 convert: dword = {bf16(lo), bf16(hi)<<16}, RNE (T12 primitive)
static __device__ __forceinline__ unsigned cvt_pk_bf16(float lo, float hi) {
  unsigned r;
  asm("v_cvt_pk_bf16_f32 %0, %1, %2" : "=v"(r) : "v"(lo), "v"(hi));
  return r;
}

static __device__ __forceinline__ float fast_exp2(float x) {
#if __has_builtin(__builtin_amdgcn_exp2f)
  return __builtin_amdgcn_exp2f(x);
#else
  return exp2f(x);
#endif
}

#define GL2LDS16(g, l)                                              \
  __builtin_amdgcn_global_load_lds(                                 \
      (const __attribute__((address_space(1))) void*)(g),           \
      (__attribute__((address_space(3))) void*)(l), 16, 0, 0)

// ---------------------------------------------------------------------------
// Fused pre-pass: x->bf16 (blocks 0..8191), Wqkv transpose (8192..11263),
// Wproj transpose (11264..12287).
// ---------------------------------------------------------------------------
__global__ __launch_bounds__(256) void prepass(
    const float* __restrict__ x, const float* __restrict__ Wq,
    const float* __restrict__ Wp, ushort* __restrict__ xb,
    ushort* __restrict__ Wqt, ushort* __restrict__ Wpt) {
  __shared__ ushort tile[32][33];
  const int bid = blockIdx.x;
  if (bid < 8192) {
    const size_t i = ((size_t)bid * 256 + threadIdx.x) * 4;
    float4 vv = *(const float4*)(x + i);
    ushort4 o = {f2bf(vv.x), f2bf(vv.y), f2bf(vv.z), f2bf(vv.w)};
    *(ushort4*)(xb + i) = o;
    return;
  }
  const float* in;
  ushort* out;
  int N, tix;
  if (bid < 8192 + 3072) {
    in = Wq; out = Wqt; N = 3 * C_; tix = bid - 8192;
  } else {
    in = Wp; out = Wpt; N = C_; tix = bid - 11264;
  }
  const int nT = N >> 5;
  const int k0 = (tix / nT) << 5, n0 = (tix % nT) << 5;
  const int r = threadIdx.x >> 3;
  const int c4 = (threadIdx.x & 7) << 2;
  float4 v = *(const float4*)(in + (size_t)(k0 + r) * N + n0 + c4);
  tile[c4 + 0][r] = f2bf(v.x);
  tile[c4 + 1][r] = f2bf(v.y);
  tile[c4 + 2][r] = f2bf(v.z);
  tile[c4 + 3][r] = f2bf(v.w);
  __syncthreads();
  ushort4 o = {tile[r][c4], tile[r][c4 + 1], tile[r][c4 + 2], tile[r][c4 + 3]};
  *(ushort4*)(out + (size_t)(n0 + r) * C_ + k0 + c4) = o;
}

// ---------------------------------------------------------------------------
// LDS XOR-swizzle for 128 B rows: chunk (16 B) at position pos of row r holds
// global chunk pos ^ (r & 7). Staging pre-swizzles the SOURCE address.
// ---------------------------------------------------------------------------
static __device__ __forceinline__ void swz_src64(int wave, int lane, int p,
                                                 int& row, int& offU) {
  const int flat = p * 4096 + wave * 1024 + lane * 16;  // byte offset in tile
  row = flat >> 7;                    // 128 B per row
  const int pos = (flat & 127) >> 4;  // chunk index in row
  const int x = pos ^ (row & 7);
  offU = x * 8;  // element offset within the row's span
}
static __device__ __forceinline__ int swz_frag64(int r, int quad, int ko) {
  return r * 128 + (((quad | (ko << 2)) ^ (r & 7)) << 4);  // bytes
}

// ---------------------------------------------------------------------------
// GEMM 1: qkv. BM=128, BN=256, BK=64, 512 thr (8 waves, 2M x 4N, wave-tile
// 64x64). 3-slot LDS rotation (144 KB), counted vmcnt(6) at K-tile boundary
// only (never 0 until tail) -- identical hazard structure to the verified R6
// kernel. R7 change: phases merged 4 -> 2, each with a 16-MFMA cluster
// (m201's cluster size). Barriers/K-tile 9 -> 5, MFMA/barrier 3.6 -> 6.4.
// ph0: read af[0..3]+bf[0..1] (12 b128), stage 3; 16 MFMA (j0-1).
// ph1: read bf[2..3] (4 b128), stage 3; 16 MFMA (j2-3).
// ---------------------------------------------------------------------------
__global__ __launch_bounds__(512, 2) void gemm_qkv_mfma(
    const ushort* __restrict__ A, const ushort* __restrict__ Bt,
    const float* __restrict__ bias, ushort* __restrict__ q,
    ushort* __restrict__ k, ushort* __restrict__ v) {
  __shared__ __align__(16) ushort KA[3][128 * 64];
  __shared__ __align__(16) ushort KB[3][256 * 64];
  const int wave = threadIdx.x >> 6, lane = threadIdx.x & 63;
  const int c = lane & 15, quad = lane >> 4;
  const int wm = wave >> 2, wn = wave & 3;
  const int bid0 = blockIdx.x;
  const int bid = (bid0 & 7) * 96 + (bid0 >> 3);  // XCD chunking, bijective
  const int m0 = (bid / 12) << 7;
  const int n0 = (bid % 12) << 8;

  int aRow[2], aX[2], bRow[4], bX[4];
#pragma unroll
  for (int p = 0; p < 2; ++p) {
    const int flat = p * 8192 + (int)threadIdx.x * 16;
    aRow[p] = flat >> 7;
    aX[p] = (((flat & 127) >> 4) ^ (aRow[p] & 7)) * 8;
  }
#pragma unroll
  for (int p = 0; p < 4; ++p) {
    const int flat = p * 8192 + (int)threadIdx.x * 16;
    bRow[p] = flat >> 7;
    bX[p] = (((flat & 127) >> 4) ^ (bRow[p] & 7)) * 8;
  }
  int fOffA[2][4], fOffB[2][4];
#pragma unroll
  for (int ko = 0; ko < 2; ++ko) {
#pragma unroll
    for (int i = 0; i < 4; ++i)
      fOffA[ko][i] = swz_frag64(wm * 64 + i * 16 + c, quad, ko);
#pragma unroll
    for (int j = 0; j < 4; ++j)
      fOffB[ko][j] = swz_frag64(wn * 64 + j * 16 + c, quad, ko);
  }

  f32x4 acc[4][4];
#pragma unroll
  for (int i = 0; i < 4; ++i)
#pragma unroll
    for (int j = 0; j < 4; ++j) acc[i][j] = (f32x4){0.f, 0.f, 0.f, 0.f};

  // prologue: stage kt=0 -> slot0, kt=1 -> slot1 (6 loads each)
#pragma unroll
  for (int p = 0; p < 4; ++p)
    GL2LDS16(Bt + (size_t)(n0 + bRow[p]) * C_ + bX[p],
             (char*)KB[0] + p * 8192 + wave * 1024);
#pragma unroll
  for (int p = 0; p < 2; ++p)
    GL2LDS16(A + (size_t)(m0 + aRow[p]) * C_ + aX[p],
             (char*)KA[0] + p * 8192 + wave * 1024);
#pragma unroll
  for (int p = 0; p < 4; ++p)
    GL2LDS16(Bt + (size_t)(n0 + bRow[p]) * C_ + 64 + bX[p],
             (char*)KB[1] + p * 8192 + wave * 1024);
#pragma unroll
  for (int p = 0; p < 2; ++p)
    GL2LDS16(A + (size_t)(m0 + aRow[p]) * C_ + 64 + aX[p],
             (char*)KA[1] + p * 8192 + wave * 1024);
  asm volatile("s_waitcnt vmcnt(6)" ::: "memory");
  __builtin_amdgcn_s_barrier();

  int cur = 0, s2 = 2;
  for (int kt = 0; kt < 16; ++kt) {
    const int kk2 = (kt + 2) << 6;
    const bool more = (kt + 2) < 16;
    const char* la = (const char*)KA[cur];
    const char* lb = (const char*)KB[cur];
    short8 af[4][2], bf0[2][2], bf1[2][2];

    // ---- phase 0: read af (8) + bf_lo (4); stage B0,B1,A0; MFMA j0-1 ----
#pragma unroll
    for (int i = 0; i < 4; ++i)
#pragma unroll
      for (int ko = 0; ko < 2; ++ko) af[i][ko] = *(const short8*)(la + fOffA[ko][i]);
#pragma unroll
    for (int d = 0; d < 2; ++d)
#pragma unroll
      for (int ko = 0; ko < 2; ++ko) bf0[d][ko] = *(const short8*)(lb + fOffB[ko][d]);
    if (more) {
      GL2LDS16(Bt + (size_t)(n0 + bRow[0]) * C_ + kk2 + bX[0],
               (char*)KB[s2] + 0 * 8192 + wave * 1024);
      GL2LDS16(Bt + (size_t)(n0 + bRow[1]) * C_ + kk2 + bX[1],
               (char*)KB[s2] + 1 * 8192 + wave * 1024);
      GL2LDS16(A + (size_t)(m0 + aRow[0]) * C_ + kk2 + aX[0],
               (char*)KA[s2] + 0 * 8192 + wave * 1024);
    }
    __builtin_amdgcn_s_barrier();
    __builtin_amdgcn_s_setprio(1);
#pragma unroll
    for (int i = 0; i < 4; ++i)
#pragma unroll
      for (int dj = 0; dj < 2; ++dj)
#pragma unroll
        for (int ko = 0; ko < 2; ++ko)
          acc[i][dj] = __builtin_amdgcn_mfma_f32_16x16x32_bf16(
              af[i][ko], bf0[dj][ko], acc[i][dj], 0, 0, 0);
    __builtin_amdgcn_s_setprio(0);
    __builtin_amdgcn_s_barrier();

    // ---- phase 1: read bf_hi (4); stage B2,B3,A1; MFMA j2-3 ----
#pragma unroll
    for (int d = 0; d < 2; ++d)
#pragma unroll
      for (int ko = 0; ko < 2; ++ko)
        bf1[d][ko] = *(const short8*)(lb + fOffB[ko][2 + d]);
    if (more) {
      GL2LDS16(Bt + (size_t)(n0 + bRow[2]) * C_ + kk2 + bX[2],
               (char*)KB[s2] + 2 * 8192 + wave * 1024);
      GL2LDS16(Bt + (size_t)(n0 + bRow[3]) * C_ + kk2 + bX[3],
               (char*)KB[s2] + 3 * 8192 + wave * 1024);
      GL2LDS16(A + (size_t)(m0 + aRow[1]) * C_ + kk2 + aX[1],
               (char*)KA[s2] + 1 * 8192 + wave * 1024);
    }
    __builtin_amdgcn_s_barrier();
    __builtin_amdgcn_s_setprio(1);
#pragma unroll
    for (int i = 0; i < 4; ++i)
#pragma unroll
      for (int dj = 0; dj < 2; ++dj)
#pragma unroll
        for (int ko = 0; ko < 2; ++ko)
          acc[i][2 + dj] = __builtin_amdgcn_mfma_f32_16x16x32_bf16(
              af[i][ko], bf1[dj][ko], acc[i][2 + dj], 0, 0, 0);
    __builtin_amdgcn_s_setprio(0);
    __builtin_amdgcn_s_barrier();

    // ---- K-tile boundary: publish slot kt+1 (counted, never 0 mid-loop) ----
    if (kt + 1 < 16) {
      if (more)
        asm volatile("s_waitcnt vmcnt(6)" ::: "memory");
      else
        asm volatile("s_waitcnt vmcnt(0)" ::: "memory");
      __builtin_amdgcn_s_barrier();
    }
    cur = (cur == 2) ? 0 : cur + 1;
    s2 = (s2 == 2) ? 0 : s2 + 1;
  }

  const int s = n0 >> 10;  // uniform per block (BN=256 divides 1024)
  if (s == 2) {
    // v epilogue: [B,H,D,T], reg r spans 4 consecutive t -> ushort4
#pragma unroll
    for (int j = 0; j < 4; ++j) {
      const int n = n0 + wn * 64 + j * 16 + c;
      const int h = (n >> 6) & 15, d = n & 63;
      const float bval = bias[n];
#pragma unroll
      for (int i = 0; i < 4; ++i) {
        const int m = m0 + wm * 64 + i * 16 + quad * 4;
        const int b = m >> 11, t = m & 2047;
        ushort4 pk = {f2bf(acc[i][j][0] + bval), f2bf(acc[i][j][1] + bval),
                      f2bf(acc[i][j][2] + bval), f2bf(acc[i][j][3] + bval)};
        *(ushort4*)(v + (((size_t)((b << 4) + h) << 6) + d) * T_ + t) = pk;
      }
    }
  } else {
    ushort* outp = (s == 0) ? q : k;
    const float sc = (s == 0) ? QSCALE : 1.0f;
#pragma unroll
    for (int j = 0; j < 4; ++j) {
      const int n = n0 + wn * 64 + j * 16 + c;
      const int h = (n >> 6) & 15, d = n & 63;
      const float bval = bias[n];
#pragma unroll
      for (int i = 0; i < 4; ++i) {
#pragma unroll
        for (int r = 0; r < 4; ++r) {
          const int m = m0 + wm * 64 + i * 16 + quad * 4 + r;
          const int b = m >> 11, t = m & 2047;
          outp[(((size_t)((b << 4) + h) << 11) + t) * 64 + d] =
              f2bf((acc[i][j][r] + bval) * sc);
        }
      }
    }
  }
}

// ---------------------------------------------------------------------------
// GEMM 2: out = y2 @ Wproj + bproj (fp32 out). R5 2-phase 128x128 version
// (multi-block overlap, proven best for proj; R6's 1-block/CU 8-phase cost
// +14 us). BK=64, grid (8, 64), XCD-aware bijective swizzle.
// ---------------------------------------------------------------------------
__global__ __launch_bounds__(256) void gemm_proj_mfma(
    const ushort* __restrict__ A, const ushort* __restrict__ Bt,
    const float* __restrict__ bias, float* __restrict__ out) {
  __shared__ __align__(16) ushort As[128 * 64];
  __shared__ __align__(16) ushort Bs[128 * 64];
  const int tid = threadIdx.x;
  const int wave = tid >> 6, lane = tid & 63;
  const int c = lane & 15, quad = lane >> 4;
  const int wm = wave & 1, wn = wave >> 1;
  const int bid0 = blockIdx.y * 8 + blockIdx.x;
  const int bid = (bid0 & 7) * 64 + (bid0 >> 3);  // XCD chunking, bijective
  const int m0 = (bid >> 3) << 7;
  const int n0 = (bid & 7) << 7;

  int sRow[4], sOff[4];
#pragma unroll
  for (int p = 0; p < 4; ++p) swz_src64(wave, lane, p, sRow[p], sOff[p]);
  int fOffA[2][4], fOffB[2][4];
#pragma unroll
  for (int ko = 0; ko < 2; ++ko) {
#pragma unroll
    for (int i = 0; i < 4; ++i)
      fOffA[ko][i] = swz_frag64(wm * 64 + i * 16 + c, quad, ko);
#pragma unroll
    for (int j = 0; j < 4; ++j)
      fOffB[ko][j] = swz_frag64(wn * 64 + j * 16 + c, quad, ko);
  }

  f32x4 acc[4][4];
#pragma unroll
  for (int i = 0; i < 4; ++i)
#pragma unroll
    for (int j = 0; j < 4; ++j) acc[i][j] = (f32x4){0.f, 0.f, 0.f, 0.f};

  for (int k0 = 0; k0 < C_; k0 += 64) {
    __syncthreads();
#pragma unroll
    for (int p = 0; p < 4; ++p) {
      GL2LDS16(A + (size_t)(m0 + sRow[p]) * C_ + k0 + sOff[p],
               (char*)As + p * 4096 + wave * 1024);
      GL2LDS16(Bt + (size_t)(n0 + sRow[p]) * C_ + k0 + sOff[p],
               (char*)Bs + p * 4096 + wave * 1024);
    }
    __syncthreads();
#pragma unroll
    for (int ko = 0; ko < 2; ++ko) {
      short8 af[4], bf[4];
#pragma unroll
      for (int i = 0; i < 4; ++i)
        af[i] = *(const short8*)((const char*)As + fOffA[ko][i]);
#pragma unroll
      for (int j = 0; j < 4; ++j)
        bf[j] = *(const short8*)((const char*)Bs + fOffB[ko][j]);
#pragma unroll
      for (int i = 0; i < 4; ++i)
#pragma unroll
        for (int j = 0; j < 4; ++j)
          acc[i][j] = __builtin_amdgcn_mfma_f32_16x16x32_bf16(af[i], bf[j],
                                                              acc[i][j], 0, 0, 0);
    }
  }

#pragma unroll
  for (int j = 0; j < 4; ++j) {
    const int n = n0 + wn * 64 + j * 16 + c;
    const float bval = bias[n];
#pragma unroll
    for (int i = 0; i < 4; ++i) {
#pragma unroll
      for (int r = 0; r < 4; ++r) {
        const int m = m0 + wm * 64 + i * 16 + quad * 4 + r;
        out[(size_t)m * C_ + n] = acc[i][j][r] + bval;
      }
    }
  }
}

// ---------------------------------------------------------------------------
// Flash attention v8: async double-buffered K/V staging via global_load_lds
// (pre-swizzled source + swizzled frag reads), ONE barrier per KV-tile,
// stage-in-flight during compute. 3 blocks/CU + 256-block HW backfill queue.
// ---------------------------------------------------------------------------
__global__ __launch_bounds__(256) void attn(const ushort* __restrict__ q,
                                            const ushort* __restrict__ k,
                                            const ushort* __restrict__ v,
                                            ushort* __restrict__ y2) {
  const int qt = 15 - (int)(blockIdx.x >> 6);  // long tiles first
  const int bh = blockIdx.x & 63;
  const int t0 = qt << 7;
  const int w = threadIdx.x >> 6;
  const int lane = threadIdx.x & 63;
  const int c = lane & 15;
  const int quad = lane >> 4;

  const ushort* qp = q + (size_t)bh * T_ * D_;
  const ushort* kp = k + (size_t)bh * T_ * D_;
  const ushort* vp = v + (size_t)bh * D_ * T_;  // [d][t]

  __shared__ __align__(16) ushort Ks[2][64 * 64];  // [key][d], swizzled rows
  __shared__ __align__(16) ushort Vs[2][64 * 64];  // [d][key], swizzled rows
  __shared__ __align__(16) ushort Ps[4][32][72];   // per-wave [query][key]

  short8 qf[2][2];
#pragma unroll
  for (int g = 0; g < 2; ++g) {
    const ushort* qrow = qp + (size_t)(t0 + 32 * w + 16 * g + c) * D_;
    qf[g][0] = *(const short8*)(qrow + quad * 8);
    qf[g][1] = *(const short8*)(qrow + 32 + quad * 8);
  }

  int sRow[2], sX[2];
#pragma unroll
  for (int p = 0; p < 2; ++p) {
    const int flat = p * 4096 + (int)threadIdx.x * 16;
    sRow[p] = flat >> 7;
    sX[p] = (((flat & 127) >> 4) ^ (sRow[p] & 7)) * 8;  // ushort offset
  }

#define STAGE(buf, s0s)                                                   \
  do {                                                                    \
    _Pragma("unroll") for (int p = 0; p < 2; ++p) {                       \
      GL2LDS16(kp + (size_t)((s0s) + sRow[p]) * D_ + sX[p],               \
               (char*)Ks[buf] + p * 4096 + w * 1024);                     \
      GL2LDS16(vp + (size_t)sRow[p] * T_ + (s0s) + sX[p],                 \
               (char*)Vs[buf] + p * 4096 + w * 1024);                     \
    }                                                                     \
  } while (0)

  f32x4 o[2][4];
  float l_i[2] = {0.f, 0.f};
#pragma unroll
  for (int g = 0; g < 2; ++g)
#pragma unroll
    for (int dt = 0; dt < 4; ++dt) o[g][dt] = (f32x4){0.f, 0.f, 0.f, 0.f};

  const int nb = 2 * qt + 2;
  STAGE(0, 0);  // prologue: tile 0 in flight
  int cur = 0;

  for (int ib = 0; ib < nb; ++ib) {
    const int s0 = ib << 6;
    // compiler drains vmcnt+lgkmcnt before s_barrier -> buf[cur] visible
    __syncthreads();
    if (ib + 1 < nb) STAGE(cur ^ 1, s0 + 64);  // in flight across compute

    // ---- S^T = K Q^T, K-frags read once, shared across both q-tiles ----
    f32x4 st[2][4];
    __builtin_amdgcn_s_setprio(1);
#pragma unroll
    for (int kt = 0; kt < 4; ++kt) {
      const char* kb = (const char*)Ks[cur];
      short8 af0 = *(const short8*)(kb + swz_frag64(kt * 16 + c, quad, 0));
      short8 af1 = *(const short8*)(kb + swz_frag64(kt * 16 + c, quad, 1));
#pragma unroll
      for (int g = 0; g < 2; ++g) {
        f32x4 a = (f32x4){0.f, 0.f, 0.f, 0.f};
        a = __builtin_amdgcn_mfma_f32_16x16x32_bf16(af0, qf[g][0], a, 0, 0, 0);
        a = __builtin_amdgcn_mfma_f32_16x16x32_bf16(af1, qf[g][1], a, 0, 0, 0);
        st[g][kt] = a;
      }
    }
    __builtin_amdgcn_s_setprio(0);

#pragma unroll
    for (int g = 0; g < 2; ++g) {
      const int qbase = t0 + 32 * w + 16 * g;
      if (s0 + 63 > qbase) {  // causal mask for this (wave, g)
#pragma unroll
        for (int kt = 0; kt < 4; ++kt)
#pragma unroll
          for (int r = 0; r < 4; ++r)
            if (s0 + kt * 16 + 4 * quad + r > qbase + c) st[g][kt][r] = -1e30f;
      }
      float lacc = 0.f;
#pragma unroll
      for (int kt = 0; kt < 4; ++kt) {
        float p0 = fast_exp2(st[g][kt][0]);
        float p1 = fast_exp2(st[g][kt][1]);
        float p2 = fast_exp2(st[g][kt][2]);
        float p3 = fast_exp2(st[g][kt][3]);
        lacc += (p0 + p1) + (p2 + p3);
        uint2 pw = {cvt_pk_bf16(p0, p1), cvt_pk_bf16(p2, p3)};
        *(uint2*)(&Ps[w][g * 16 + c][kt * 16 + 4 * quad]) = pw;
      }
      l_i[g] += lacc;
    }

    // ---- O^T += V^T P^T (V-frags shared across both q-tiles) ----
    short8 pf[2][2];
#pragma unroll
    for (int g = 0; g < 2; ++g) {
      pf[g][0] = *(const short8*)(&Ps[w][g * 16 + c][quad * 8]);
      pf[g][1] = *(const short8*)(&Ps[w][g * 16 + c][32 + quad * 8]);
    }
    __builtin_amdgcn_s_setprio(1);
#pragma unroll
    for (int dt = 0; dt < 4; ++dt) {
      const char* vb = (const char*)Vs[cur];
      short8 vf0 = *(const short8*)(vb + swz_frag64(dt * 16 + c, quad, 0));
      short8 vf1 = *(const short8*)(vb + swz_frag64(dt * 16 + c, quad, 1));
#pragma unroll
      for (int g = 0; g < 2; ++g) {
        o[g][dt] =
            __builtin_amdgcn_mfma_f32_16x16x32_bf16(vf0, pf[g][0], o[g][dt], 0, 0, 0);
        o[g][dt] =
            __builtin_amdgcn_mfma_f32_16x16x32_bf16(vf1, pf[g][1], o[g][dt], 0, 0, 0);
      }
    }
    __builtin_amdgcn_s_setprio(0);
    cur ^= 1;
  }
#undef STAGE

  float linv[2];
#pragma unroll
  for (int g = 0; g < 2; ++g) {
    float ls = l_i[g];
    ls += __shfl_xor(ls, 16);
    ls += __shfl_xor(ls, 32);
    linv[g] = 1.0f / ls;
  }

  const int b = bh >> 4, h = bh & 15;
#pragma unroll
  for (int g = 0; g < 2; ++g) {
    const int row = t0 + 32 * w + 16 * g + c;
    ushort* dst = y2 + (size_t)(b * T_ + row) * C_ + h * 64;
#pragma unroll
    for (int dt = 0; dt < 4; ++dt) {
      uint2 ov = {cvt_pk_bf16(o[g][dt][0] * linv[g], o[g][dt][1] * linv[g]),
                  cvt_pk_bf16(o[g][dt][2] * linv[g], o[g][dt][3] * linv[g])};
      *(uint2*)(dst + dt * 16 + 4 * quad) = ov;
    }
  }
}

// ---------------------------------------------------------------------------
extern "C" void kernel_launch(void* const* d_in, const int* in_sizes, int n_in,
                              void* d_out, int out_size, void* d_ws,
                              size_t ws_size, hipStream_t stream) {
  const float* x = (const float*)d_in[0];
  const float* Wqkv = (const float*)d_in[1];
  const float* bqkv = (const float*)d_in[2];
  const float* Wproj = (const float*)d_in[3];
  const float* bproj = (const float*)d_in[4];
  float* out = (float*)d_out;

  const size_t per = (size_t)B_ * H_ * T_ * D_;  // 8388608
  ushort* q = (ushort*)d_ws;
  ushort* k = q + per;
  ushort* v = k + per;  // [B,H,D,T]
  ushort* y2 = v + per;
  ushort* xb = y2 + per;
  ushort* Wqkvt = xb + per;              // [3072][1024]
  ushort* Wprojt = Wqkvt + 3 * C_ * C_;  // [1024][1024]

  prepass<<<dim3(12288), 256, 0, stream>>>(x, Wqkv, Wproj, xb, Wqkvt, Wprojt);
  gemm_qkv_mfma<<<dim3(768), 512, 0, stream>>>(xb, Wqkvt, bqkv, q, k, v);
  attn<<<dim3(1024), 256, 0, stream>>>(q, k, v, y2);
  gemm_proj_mfma<<<dim3(8, 64), 256, 0, stream>>>(y2, Wprojt, bproj, out);
}

// Round 8
// 249.304 us; speedup vs baseline: 1.0382x; 1.0382x over previous
//
#include <hip/hip_runtime.h>
#include <hip/hip_bf16.h>

#define B_ 4
#define T_ 2048
#define C_ 1024
#define H_ 16
#define D_ 64

typedef __attribute__((ext_vector_type(8))) short short8;
typedef __attribute__((ext_vector_type(4))) float f32x4;

// q pre-scale: (1/sqrt(D)) * log2(e) so attn uses raw v_exp_f32 (exp2)
#define QSCALE 0.18033688011112042f

static __device__ __forceinline__ unsigned short f2bf(float f) {
  unsigned u = __float_as_uint(f);
  u += 0x7fff + ((u >> 16) & 1);  // round-to-nearest-even
  return (unsigned short)(u >> 16);
}

// packed bf16 convert: dword = {bf16(lo), bf16(hi)<<16}, RNE (T12 primitive)
static __device__ __forceinline__ unsigned cvt_pk_bf16(float lo, float hi) {
  unsigned r;
  asm("v_cvt_pk_bf16_f32 %0, %1, %2" : "=v"(r) : "v"(lo), "v"(hi));
  return r;
}

static __device__ __forceinline__ float fast_exp2(float x) {
#if __has_builtin(__builtin_amdgcn_exp2f)
  return __builtin_amdgcn_exp2f(x);
#else
  return exp2f(x);
#endif
}

#define GL2LDS16(g, l)                                              \
  __builtin_amdgcn_global_load_lds(                                 \
      (const __attribute__((address_space(1))) void*)(g),           \
      (__attribute__((address_space(3))) void*)(l), 16, 0, 0)

// ---------------------------------------------------------------------------
// Fused pre-pass: x->bf16 (blocks 0..8191), Wqkv transpose (8192..11263),
// Wproj transpose (11264..12287).
// ---------------------------------------------------------------------------
__global__ __launch_bounds__(256) void prepass(
    const float* __restrict__ x, const float* __restrict__ Wq,
    const float* __restrict__ Wp, ushort* __restrict__ xb,
    ushort* __restrict__ Wqt, ushort* __restrict__ Wpt) {
  __shared__ ushort tile[32][33];
  const int bid = blockIdx.x;
  if (bid < 8192) {
    const size_t i = ((size_t)bid * 256 + threadIdx.x) * 4;
    float4 vv = *(const float4*)(x + i);
    ushort4 o = {f2bf(vv.x), f2bf(vv.y), f2bf(vv.z), f2bf(vv.w)};
    *(ushort4*)(xb + i) = o;
    return;
  }
  const float* in;
  ushort* out;
  int N, tix;
  if (bid < 8192 + 3072) {
    in = Wq; out = Wqt; N = 3 * C_; tix = bid - 8192;
  } else {
    in = Wp; out = Wpt; N = C_; tix = bid - 11264;
  }
  const int nT = N >> 5;
  const int k0 = (tix / nT) << 5, n0 = (tix % nT) << 5;
  const int r = threadIdx.x >> 3;
  const int c4 = (threadIdx.x & 7) << 2;
  float4 v = *(const float4*)(in + (size_t)(k0 + r) * N + n0 + c4);
  tile[c4 + 0][r] = f2bf(v.x);
  tile[c4 + 1][r] = f2bf(v.y);
  tile[c4 + 2][r] = f2bf(v.z);
  tile[c4 + 3][r] = f2bf(v.w);
  __syncthreads();
  ushort4 o = {tile[r][c4], tile[r][c4 + 1], tile[r][c4 + 2], tile[r][c4 + 3]};
  *(ushort4*)(out + (size_t)(n0 + r) * C_ + k0 + c4) = o;
}

// ---------------------------------------------------------------------------
// LDS XOR-swizzle for 128 B rows: chunk (16 B) at position pos of row r holds
// global chunk pos ^ (r & 7). Staging pre-swizzles the SOURCE address.
// ---------------------------------------------------------------------------
static __device__ __forceinline__ void swz_src64(int wave, int lane, int p,
                                                 int& row, int& offU) {
  const int flat = p * 4096 + wave * 1024 + lane * 16;  // byte offset in tile
  row = flat >> 7;                    // 128 B per row
  const int pos = (flat & 127) >> 4;  // chunk index in row
  const int x = pos ^ (row & 7);
  offU = x * 8;  // element offset within the row's span
}
static __device__ __forceinline__ int swz_frag64(int r, int quad, int ko) {
  return r * 128 + (((quad | (ko << 2)) ^ (r & 7)) << 4);  // bytes
}

// ---------------------------------------------------------------------------
// GEMM 1: qkv (R7 best-measured: 74 us). BM=128, BN=256, BK=64, 512 thr,
// 3-slot LDS rotation, counted vmcnt(6), 2 merged phases of 16 MFMA.
// ---------------------------------------------------------------------------
__global__ __launch_bounds__(512, 2) void gemm_qkv_mfma(
    const ushort* __restrict__ A, const ushort* __restrict__ Bt,
    const float* __restrict__ bias, ushort* __restrict__ q,
    ushort* __restrict__ k, ushort* __restrict__ v) {
  __shared__ __align__(16) ushort KA[3][128 * 64];
  __shared__ __align__(16) ushort KB[3][256 * 64];
  const int wave = threadIdx.x >> 6, lane = threadIdx.x & 63;
  const int c = lane & 15, quad = lane >> 4;
  const int wm = wave >> 2, wn = wave & 3;
  const int bid0 = blockIdx.x;
  const int bid = (bid0 & 7) * 96 + (bid0 >> 3);  // XCD chunking, bijective
  const int m0 = (bid / 12) << 7;
  const int n0 = (bid % 12) << 8;

  int aRow[2], aX[2], bRow[4], bX[4];
#pragma unroll
  for (int p = 0; p < 2; ++p) {
    const int flat = p * 8192 + (int)threadIdx.x * 16;
    aRow[p] = flat >> 7;
    aX[p] = (((flat & 127) >> 4) ^ (aRow[p] & 7)) * 8;
  }
#pragma unroll
  for (int p = 0; p < 4; ++p) {
    const int flat = p * 8192 + (int)threadIdx.x * 16;
    bRow[p] = flat >> 7;
    bX[p] = (((flat & 127) >> 4) ^ (bRow[p] & 7)) * 8;
  }
  int fOffA[2][4], fOffB[2][4];
#pragma unroll
  for (int ko = 0; ko < 2; ++ko) {
#pragma unroll
    for (int i = 0; i < 4; ++i)
      fOffA[ko][i] = swz_frag64(wm * 64 + i * 16 + c, quad, ko);
#pragma unroll
    for (int j = 0; j < 4; ++j)
      fOffB[ko][j] = swz_frag64(wn * 64 + j * 16 + c, quad, ko);
  }

  f32x4 acc[4][4];
#pragma unroll
  for (int i = 0; i < 4; ++i)
#pragma unroll
    for (int j = 0; j < 4; ++j) acc[i][j] = (f32x4){0.f, 0.f, 0.f, 0.f};

  // prologue: stage kt=0 -> slot0, kt=1 -> slot1 (6 loads each)
#pragma unroll
  for (int p = 0; p < 4; ++p)
    GL2LDS16(Bt + (size_t)(n0 + bRow[p]) * C_ + bX[p],
             (char*)KB[0] + p * 8192 + wave * 1024);
#pragma unroll
  for (int p = 0; p < 2; ++p)
    GL2LDS16(A + (size_t)(m0 + aRow[p]) * C_ + aX[p],
             (char*)KA[0] + p * 8192 + wave * 1024);
#pragma unroll
  for (int p = 0; p < 4; ++p)
    GL2LDS16(Bt + (size_t)(n0 + bRow[p]) * C_ + 64 + bX[p],
             (char*)KB[1] + p * 8192 + wave * 1024);
#pragma unroll
  for (int p = 0; p < 2; ++p)
    GL2LDS16(A + (size_t)(m0 + aRow[p]) * C_ + 64 + aX[p],
             (char*)KA[1] + p * 8192 + wave * 1024);
  asm volatile("s_waitcnt vmcnt(6)" ::: "memory");
  __builtin_amdgcn_s_barrier();

  int cur = 0, s2 = 2;
  for (int kt = 0; kt < 16; ++kt) {
    const int kk2 = (kt + 2) << 6;
    const bool more = (kt + 2) < 16;
    const char* la = (const char*)KA[cur];
    const char* lb = (const char*)KB[cur];
    short8 af[4][2], bf0[2][2], bf1[2][2];

    // ---- phase 0: read af (8) + bf_lo (4); stage B0,B1,A0; MFMA j0-1 ----
#pragma unroll
    for (int i = 0; i < 4; ++i)
#pragma unroll
      for (int ko = 0; ko < 2; ++ko) af[i][ko] = *(const short8*)(la + fOffA[ko][i]);
#pragma unroll
    for (int d = 0; d < 2; ++d)
#pragma unroll
      for (int ko = 0; ko < 2; ++ko) bf0[d][ko] = *(const short8*)(lb + fOffB[ko][d]);
    if (more) {
      GL2LDS16(Bt + (size_t)(n0 + bRow[0]) * C_ + kk2 + bX[0],
               (char*)KB[s2] + 0 * 8192 + wave * 1024);
      GL2LDS16(Bt + (size_t)(n0 + bRow[1]) * C_ + kk2 + bX[1],
               (char*)KB[s2] + 1 * 8192 + wave * 1024);
      GL2LDS16(A + (size_t)(m0 + aRow[0]) * C_ + kk2 + aX[0],
               (char*)KA[s2] + 0 * 8192 + wave * 1024);
    }
    __builtin_amdgcn_s_barrier();
    __builtin_amdgcn_s_setprio(1);
#pragma unroll
    for (int i = 0; i < 4; ++i)
#pragma unroll
      for (int dj = 0; dj < 2; ++dj)
#pragma unroll
        for (int ko = 0; ko < 2; ++ko)
          acc[i][dj] = __builtin_amdgcn_mfma_f32_16x16x32_bf16(
              af[i][ko], bf0[dj][ko], acc[i][dj], 0, 0, 0);
    __builtin_amdgcn_s_setprio(0);
    __builtin_amdgcn_s_barrier();

    // ---- phase 1: read bf_hi (4); stage B2,B3,A1; MFMA j2-3 ----
#pragma unroll
    for (int d = 0; d < 2; ++d)
#pragma unroll
      for (int ko = 0; ko < 2; ++ko)
        bf1[d][ko] = *(const short8*)(lb + fOffB[ko][2 + d]);
    if (more) {
      GL2LDS16(Bt + (size_t)(n0 + bRow[2]) * C_ + kk2 + bX[2],
               (char*)KB[s2] + 2 * 8192 + wave * 1024);
      GL2LDS16(Bt + (size_t)(n0 + bRow[3]) * C_ + kk2 + bX[3],
               (char*)KB[s2] + 3 * 8192 + wave * 1024);
      GL2LDS16(A + (size_t)(m0 + aRow[1]) * C_ + kk2 + aX[1],
               (char*)KA[s2] + 1 * 8192 + wave * 1024);
    }
    __builtin_amdgcn_s_barrier();
    __builtin_amdgcn_s_setprio(1);
#pragma unroll
    for (int i = 0; i < 4; ++i)
#pragma unroll
      for (int dj = 0; dj < 2; ++dj)
#pragma unroll
        for (int ko = 0; ko < 2; ++ko)
          acc[i][2 + dj] = __builtin_amdgcn_mfma_f32_16x16x32_bf16(
              af[i][ko], bf1[dj][ko], acc[i][2 + dj], 0, 0, 0);
    __builtin_amdgcn_s_setprio(0);
    __builtin_amdgcn_s_barrier();

    // ---- K-tile boundary: publish slot kt+1 (counted, never 0 mid-loop) ----
    if (kt + 1 < 16) {
      if (more)
        asm volatile("s_waitcnt vmcnt(6)" ::: "memory");
      else
        asm volatile("s_waitcnt vmcnt(0)" ::: "memory");
      __builtin_amdgcn_s_barrier();
    }
    cur = (cur == 2) ? 0 : cur + 1;
    s2 = (s2 == 2) ? 0 : s2 + 1;
  }

  const int s = n0 >> 10;  // uniform per block (BN=256 divides 1024)
  if (s == 2) {
    // v epilogue: [B,H,D,T], reg r spans 4 consecutive t -> ushort4
#pragma unroll
    for (int j = 0; j < 4; ++j) {
      const int n = n0 + wn * 64 + j * 16 + c;
      const int h = (n >> 6) & 15, d = n & 63;
      const float bval = bias[n];
#pragma unroll
      for (int i = 0; i < 4; ++i) {
        const int m = m0 + wm * 64 + i * 16 + quad * 4;
        const int b = m >> 11, t = m & 2047;
        ushort4 pk = {f2bf(acc[i][j][0] + bval), f2bf(acc[i][j][1] + bval),
                      f2bf(acc[i][j][2] + bval), f2bf(acc[i][j][3] + bval)};
        *(ushort4*)(v + (((size_t)((b << 4) + h) << 6) + d) * T_ + t) = pk;
      }
    }
  } else {
    ushort* outp = (s == 0) ? q : k;
    const float sc = (s == 0) ? QSCALE : 1.0f;
#pragma unroll
    for (int j = 0; j < 4; ++j) {
      const int n = n0 + wn * 64 + j * 16 + c;
      const int h = (n >> 6) & 15, d = n & 63;
      const float bval = bias[n];
#pragma unroll
      for (int i = 0; i < 4; ++i) {
#pragma unroll
        for (int r = 0; r < 4; ++r) {
          const int m = m0 + wm * 64 + i * 16 + quad * 4 + r;
          const int b = m >> 11, t = m & 2047;
          outp[(((size_t)((b << 4) + h) << 11) + t) * 64 + d] =
              f2bf((acc[i][j][r] + bval) * sc);
        }
      }
    }
  }
}

// ---------------------------------------------------------------------------
// GEMM 2 v2: out = y2 @ Wproj + bproj (fp32 out). attn-v8 pattern: async
// double-buffered staging, ONE __syncthreads per K-tile (implicit vmcnt drain
// publishes the landed buffer), stage-in-flight across the whole compute
// phase. LDS 64 KB -> 2 blocks/CU. Grid (8, 64), bijective XCD swizzle.
// ---------------------------------------------------------------------------
__global__ __launch_bounds__(256) void gemm_proj_mfma(
    const ushort* __restrict__ A, const ushort* __restrict__ Bt,
    const float* __restrict__ bias, float* __restrict__ out) {
  __shared__ __align__(16) ushort As[2][128 * 64];
  __shared__ __align__(16) ushort Bs[2][128 * 64];
  const int tid = threadIdx.x;
  const int wave = tid >> 6, lane = tid & 63;
  const int c = lane & 15, quad = lane >> 4;
  const int wm = wave & 1, wn = wave >> 1;
  const int bid0 = blockIdx.y * 8 + blockIdx.x;
  const int bid = (bid0 & 7) * 64 + (bid0 >> 3);  // XCD chunking, bijective
  const int m0 = (bid >> 3) << 7;
  const int n0 = (bid & 7) << 7;

  int sRow[4], sOff[4];
#pragma unroll
  for (int p = 0; p < 4; ++p) swz_src64(wave, lane, p, sRow[p], sOff[p]);
  int fOffA[2][4], fOffB[2][4];
#pragma unroll
  for (int ko = 0; ko < 2; ++ko) {
#pragma unroll
    for (int i = 0; i < 4; ++i)
      fOffA[ko][i] = swz_frag64(wm * 64 + i * 16 + c, quad, ko);
#pragma unroll
    for (int j = 0; j < 4; ++j)
      fOffB[ko][j] = swz_frag64(wn * 64 + j * 16 + c, quad, ko);
  }

  f32x4 acc[4][4];
#pragma unroll
  for (int i = 0; i < 4; ++i)
#pragma unroll
    for (int j = 0; j < 4; ++j) acc[i][j] = (f32x4){0.f, 0.f, 0.f, 0.f};

#define PROJ_STAGE(buf, kk)                                            \
  do {                                                                 \
    _Pragma("unroll") for (int p = 0; p < 4; ++p) {                    \
      GL2LDS16(A + (size_t)(m0 + sRow[p]) * C_ + (kk) + sOff[p],       \
               (char*)As[buf] + p * 4096 + wave * 1024);               \
      GL2LDS16(Bt + (size_t)(n0 + sRow[p]) * C_ + (kk) + sOff[p],      \
               (char*)Bs[buf] + p * 4096 + wave * 1024);               \
    }                                                                  \
  } while (0)

  PROJ_STAGE(0, 0);
  int cur = 0;
  for (int k0 = 0; k0 < C_; k0 += 64) {
    __syncthreads();  // drains vmcnt -> buf[cur] visible to all waves
    if (k0 + 64 < C_) PROJ_STAGE(cur ^ 1, k0 + 64);  // in flight over compute
#pragma unroll
    for (int ko = 0; ko < 2; ++ko) {
      short8 af[4], bf[4];
#pragma unroll
      for (int i = 0; i < 4; ++i)
        af[i] = *(const short8*)((const char*)As[cur] + fOffA[ko][i]);
#pragma unroll
      for (int j = 0; j < 4; ++j)
        bf[j] = *(const short8*)((const char*)Bs[cur] + fOffB[ko][j]);
      __builtin_amdgcn_s_setprio(1);
#pragma unroll
      for (int i = 0; i < 4; ++i)
#pragma unroll
        for (int j = 0; j < 4; ++j)
          acc[i][j] = __builtin_amdgcn_mfma_f32_16x16x32_bf16(af[i], bf[j],
                                                              acc[i][j], 0, 0, 0);
      __builtin_amdgcn_s_setprio(0);
    }
    cur ^= 1;
  }
#undef PROJ_STAGE

#pragma unroll
  for (int j = 0; j < 4; ++j) {
    const int n = n0 + wn * 64 + j * 16 + c;
    const float bval = bias[n];
#pragma unroll
    for (int i = 0; i < 4; ++i) {
#pragma unroll
      for (int r = 0; r < 4; ++r) {
        const int m = m0 + wm * 64 + i * 16 + quad * 4 + r;
        out[(size_t)m * C_ + n] = acc[i][j][r] + bval;
      }
    }
  }
}

// ---------------------------------------------------------------------------
// Flash attention v9: v8 async staging + Ps LDS round-trip replaced by
// register shuffles. Derivation (from the validated Ps layout): target lane
// (c,q) dword i of the PV B-fragment needs keys (8q+2i, 8q+2i+1) = source
// lane c+32(q&1)+16(i>>1)'s cvt_pk dword pw[kt_s][i&1], kt_s = q>>1 (+2 for
// keys 32-63). kt_s is target-dependent -> 2 shfl + 1 select per dword.
// LDS 50.4 -> 32 KB => 4-5 blocks/CU (occupancy = proven attn lever).
// ---------------------------------------------------------------------------
__global__ __launch_bounds__(256) void attn(const ushort* __restrict__ q,
                                            const ushort* __restrict__ k,
                                            const ushort* __restrict__ v,
                                            ushort* __restrict__ y2) {
  const int qt = 15 - (int)(blockIdx.x >> 6);  // long tiles first
  const int bh = blockIdx.x & 63;
  const int t0 = qt << 7;
  const int w = threadIdx.x >> 6;
  const int lane = threadIdx.x & 63;
  const int c = lane & 15;
  const int quad = lane >> 4;

  const ushort* qp = q + (size_t)bh * T_ * D_;
  const ushort* kp = k + (size_t)bh * T_ * D_;
  const ushort* vp = v + (size_t)bh * D_ * T_;  // [d][t]

  __shared__ __align__(16) ushort Ks[2][64 * 64];  // [key][d], swizzled rows
  __shared__ __align__(16) ushort Vs[2][64 * 64];  // [d][key], swizzled rows

  short8 qf[2][2];
#pragma unroll
  for (int g = 0; g < 2; ++g) {
    const ushort* qrow = qp + (size_t)(t0 + 32 * w + 16 * g + c) * D_;
    qf[g][0] = *(const short8*)(qrow + quad * 8);
    qf[g][1] = *(const short8*)(qrow + 32 + quad * 8);
  }

  int sRow[2], sX[2];
#pragma unroll
  for (int p = 0; p < 2; ++p) {
    const int flat = p * 4096 + (int)threadIdx.x * 16;
    sRow[p] = flat >> 7;
    sX[p] = (((flat & 127) >> 4) ^ (sRow[p] & 7)) * 8;  // ushort offset
  }

#define STAGE(buf, s0s)                                                   \
  do {                                                                    \
    _Pragma("unroll") for (int p = 0; p < 2; ++p) {                       \
      GL2LDS16(kp + (size_t)((s0s) + sRow[p]) * D_ + sX[p],               \
               (char*)Ks[buf] + p * 4096 + w * 1024);                     \
      GL2LDS16(vp + (size_t)sRow[p] * T_ + (s0s) + sX[p],                 \
               (char*)Vs[buf] + p * 4096 + w * 1024);                     \
    }                                                                     \
  } while (0)

  f32x4 o[2][4];
  float l_i[2] = {0.f, 0.f};
#pragma unroll
  for (int g = 0; g < 2; ++g)
#pragma unroll
    for (int dt = 0; dt < 4; ++dt) o[g][dt] = (f32x4){0.f, 0.f, 0.f, 0.f};

  const int nb = 2 * qt + 2;
  STAGE(0, 0);  // prologue: tile 0 in flight
  int cur = 0;
  const int sA = c + ((quad & 1) << 5);  // shuffle source lanes (i = 0,1)
  const int sB = sA + 16;                // (i = 2,3)

  for (int ib = 0; ib < nb; ++ib) {
    const int s0 = ib << 6;
    // compiler drains vmcnt+lgkmcnt before s_barrier -> buf[cur] visible
    __syncthreads();
    if (ib + 1 < nb) STAGE(cur ^ 1, s0 + 64);  // in flight across compute

    // ---- S^T = K Q^T, K-frags read once, shared across both q-tiles ----
    f32x4 st[2][4];
    __builtin_amdgcn_s_setprio(1);
#pragma unroll
    for (int kt = 0; kt < 4; ++kt) {
      const char* kb = (const char*)Ks[cur];
      short8 af0 = *(const short8*)(kb + swz_frag64(kt * 16 + c, quad, 0));
      short8 af1 = *(const short8*)(kb + swz_frag64(kt * 16 + c, quad, 1));
#pragma unroll
      for (int g = 0; g < 2; ++g) {
        f32x4 a = (f32x4){0.f, 0.f, 0.f, 0.f};
        a = __builtin_amdgcn_mfma_f32_16x16x32_bf16(af0, qf[g][0], a, 0, 0, 0);
        a = __builtin_amdgcn_mfma_f32_16x16x32_bf16(af1, qf[g][1], a, 0, 0, 0);
        st[g][kt] = a;
      }
    }
    __builtin_amdgcn_s_setprio(0);

    // ---- softmax: mask + exp2 + packed bf16 (kept in registers) ----
    unsigned pw[2][4][2];  // [g][kt][b]
#pragma unroll
    for (int g = 0; g < 2; ++g) {
      const int qbase = t0 + 32 * w + 16 * g;
      if (s0 + 63 > qbase) {  // causal mask for this (wave, g)
#pragma unroll
        for (int kt = 0; kt < 4; ++kt)
#pragma unroll
          for (int r = 0; r < 4; ++r)
            if (s0 + kt * 16 + 4 * quad + r > qbase + c) st[g][kt][r] = -1e30f;
      }
      float lacc = 0.f;
#pragma unroll
      for (int kt = 0; kt < 4; ++kt) {
        float p0 = fast_exp2(st[g][kt][0]);
        float p1 = fast_exp2(st[g][kt][1]);
        float p2 = fast_exp2(st[g][kt][2]);
        float p3 = fast_exp2(st[g][kt][3]);
        lacc += (p0 + p1) + (p2 + p3);
        pw[g][kt][0] = cvt_pk_bf16(p0, p1);
        pw[g][kt][1] = cvt_pk_bf16(p2, p3);
      }
      l_i[g] += lacc;
    }

    // ---- P^T repack via shuffles (replaces Ps LDS round-trip) ----
    short8 pf[2][2];
#pragma unroll
    for (int g = 0; g < 2; ++g) {
#pragma unroll
      for (int half = 0; half < 2; ++half) {
        const unsigned lo0 = pw[g][half * 2][0], lo1 = pw[g][half * 2][1];
        const unsigned hi0 = pw[g][half * 2 + 1][0], hi1 = pw[g][half * 2 + 1][1];
        const unsigned a0 = (unsigned)__shfl((int)lo0, sA);
        const unsigned b0 = (unsigned)__shfl((int)hi0, sA);
        const unsigned a1 = (unsigned)__shfl((int)lo1, sA);
        const unsigned b1 = (unsigned)__shfl((int)hi1, sA);
        const unsigned a2 = (unsigned)__shfl((int)lo0, sB);
        const unsigned b2 = (unsigned)__shfl((int)hi0, sB);
        const unsigned a3 = (unsigned)__shfl((int)lo1, sB);
        const unsigned b3 = (unsigned)__shfl((int)hi1, sB);
        uint4 r;
        r.x = (quad & 2) ? b0 : a0;
        r.y = (quad & 2) ? b1 : a1;
        r.z = (quad & 2) ? b2 : a2;
        r.w = (quad & 2) ? b3 : a3;
        pf[g][half] = *(short8*)&r;
      }
    }

    // ---- O^T += V^T P^T (V-frags shared across both q-tiles) ----
    __builtin_amdgcn_s_setprio(1);
#pragma unroll
    for (int dt = 0; dt < 4; ++dt) {
      const char* vb = (const char*)Vs[cur];
      short8 vf0 = *(const short8*)(vb + swz_frag64(dt * 16 + c, quad, 0));
      short8 vf1 = *(const short8*)(vb + swz_frag64(dt * 16 + c, quad, 1));
#pragma unroll
      for (int g = 0; g < 2; ++g) {
        o[g][dt] =
            __builtin_amdgcn_mfma_f32_16x16x32_bf16(vf0, pf[g][0], o[g][dt], 0, 0, 0);
        o[g][dt] =
            __builtin_amdgcn_mfma_f32_16x16x32_bf16(vf1, pf[g][1], o[g][dt], 0, 0, 0);
      }
    }
    __builtin_amdgcn_s_setprio(0);
    cur ^= 1;
  }
#undef STAGE

  float linv[2];
#pragma unroll
  for (int g = 0; g < 2; ++g) {
    float ls = l_i[g];
    ls += __shfl_xor(ls, 16);
    ls += __shfl_xor(ls, 32);
    linv[g] = 1.0f / ls;
  }

  const int b = bh >> 4, h = bh & 15;
#pragma unroll
  for (int g = 0; g < 2; ++g) {
    const int row = t0 + 32 * w + 16 * g + c;
    ushort* dst = y2 + (size_t)(b * T_ + row) * C_ + h * 64;
#pragma unroll
    for (int dt = 0; dt < 4; ++dt) {
      uint2 ov = {cvt_pk_bf16(o[g][dt][0] * linv[g], o[g][dt][1] * linv[g]),
                  cvt_pk_bf16(o[g][dt][2] * linv[g], o[g][dt][3] * linv[g])};
      *(uint2*)(dst + dt * 16 + 4 * quad) = ov;
    }
  }
}

// ---------------------------------------------------------------------------
extern "C" void kernel_launch(void* const* d_in, const int* in_sizes, int n_in,
                              void* d_out, int out_size, void* d_ws,
                              size_t ws_size, hipStream_t stream) {
  const float* x = (const float*)d_in[0];
  const float* Wqkv = (const float*)d_in[1];
  const float* bqkv = (const float*)d_in[2];
  const float* Wproj = (const float*)d_in[3];
  const float* bproj = (const float*)d_in[4];
  float* out = (float*)d_out;

  const size_t per = (size_t)B_ * H_ * T_ * D_;  // 8388608
  ushort* q = (ushort*)d_ws;
  ushort* k = q + per;
  ushort* v = k + per;  // [B,H,D,T]
  ushort* y2 = v + per;
  ushort* xb = y2 + per;
  ushort* Wqkvt = xb + per;              // [3072][1024]
  ushort* Wprojt = Wqkvt + 3 * C_ * C_;  // [1024][1024]

  prepass<<<dim3(12288), 256, 0, stream>>>(x, Wqkv, Wproj, xb, Wqkvt, Wprojt);
  gemm_qkv_mfma<<<dim3(768), 512, 0, stream>>>(xb, Wqkvt, bqkv, q, k, v);
  attn<<<dim3(1024), 256, 0, stream>>>(q, k, v, y2);
  gemm_proj_mfma<<<dim3(8, 64), 256, 0, stream>>>(y2, Wprojt, bproj, out);
}

// Round 9
// 245.704 us; speedup vs baseline: 1.0535x; 1.0147x over previous
//
#include <hip/hip_runtime.h>
#include <hip/hip_bf16.h>

#define B_ 4
#define T_ 2048
#define C_ 1024
#define H_ 16
#define D_ 64

typedef __attribute__((ext_vector_type(8))) short short8;
typedef __attribute__((ext_vector_type(4))) float f32x4;

// q pre-scale: (1/sqrt(D)) * log2(e) so attn uses raw v_exp_f32 (exp2)
#define QSCALE 0.18033688011112042f

static __device__ __forceinline__ unsigned short f2bf(float f) {
  unsigned u = __float_as_uint(f);
  u += 0x7fff + ((u >> 16) & 1);  // round-to-nearest-even
  return (unsigned short)(u >> 16);
}

// packed bf16 convert: dword = {bf16(lo), bf16(hi)<<16}, RNE (T12 primitive)
static __device__ __forceinline__ unsigned cvt_pk_bf16(float lo, float hi) {
  unsigned r;
  asm("v_cvt_pk_bf16_f32 %0, %1, %2" : "=v"(r) : "v"(lo), "v"(hi));
  return r;
}

static __device__ __forceinline__ float fast_exp2(float x) {
#if __has_builtin(__builtin_amdgcn_exp2f)
  return __builtin_amdgcn_exp2f(x);
#else
  return exp2f(x);
#endif
}

#define GL2LDS16(g, l)                                              \
  __builtin_amdgcn_global_load_lds(                                 \
      (const __attribute__((address_space(1))) void*)(g),           \
      (__attribute__((address_space(3))) void*)(l), 16, 0, 0)

// ---------------------------------------------------------------------------
// Fused pre-pass: x->bf16 (blocks 0..8191), Wqkv transpose (8192..11263),
// Wproj transpose (11264..12287).
// ---------------------------------------------------------------------------
__global__ __launch_bounds__(256) void prepass(
    const float* __restrict__ x, const float* __restrict__ Wq,
    const float* __restrict__ Wp, ushort* __restrict__ xb,
    ushort* __restrict__ Wqt, ushort* __restrict__ Wpt) {
  __shared__ ushort tile[32][33];
  const int bid = blockIdx.x;
  if (bid < 8192) {
    const size_t i = ((size_t)bid * 256 + threadIdx.x) * 4;
    float4 vv = *(const float4*)(x + i);
    ushort4 o = {f2bf(vv.x), f2bf(vv.y), f2bf(vv.z), f2bf(vv.w)};
    *(ushort4*)(xb + i) = o;
    return;
  }
  const float* in;
  ushort* out;
  int N, tix;
  if (bid < 8192 + 3072) {
    in = Wq; out = Wqt; N = 3 * C_; tix = bid - 8192;
  } else {
    in = Wp; out = Wpt; N = C_; tix = bid - 11264;
  }
  const int nT = N >> 5;
  const int k0 = (tix / nT) << 5, n0 = (tix % nT) << 5;
  const int r = threadIdx.x >> 3;
  const int c4 = (threadIdx.x & 7) << 2;
  float4 v = *(const float4*)(in + (size_t)(k0 + r) * N + n0 + c4);
  tile[c4 + 0][r] = f2bf(v.x);
  tile[c4 + 1][r] = f2bf(v.y);
  tile[c4 + 2][r] = f2bf(v.z);
  tile[c4 + 3][r] = f2bf(v.w);
  __syncthreads();
  ushort4 o = {tile[r][c4], tile[r][c4 + 1], tile[r][c4 + 2], tile[r][c4 + 3]};
  *(ushort4*)(out + (size_t)(n0 + r) * C_ + k0 + c4) = o;
}

// ---------------------------------------------------------------------------
// LDS XOR-swizzle for 128 B rows: chunk (16 B) at position pos of row r holds
// global chunk pos ^ (r & 7). Staging pre-swizzles the SOURCE address.
// ---------------------------------------------------------------------------
static __device__ __forceinline__ void swz_src64(int wave, int lane, int p,
                                                 int& row, int& offU) {
  const int flat = p * 4096 + wave * 1024 + lane * 16;  // byte offset in tile
  row = flat >> 7;                    // 128 B per row
  const int pos = (flat & 127) >> 4;  // chunk index in row
  const int x = pos ^ (row & 7);
  offU = x * 8;  // element offset within the row's span
}
static __device__ __forceinline__ int swz_frag64(int r, int quad, int ko) {
  return r * 128 + (((quad | (ko << 2)) ^ (r & 7)) << 4);  // bytes
}

// ---------------------------------------------------------------------------
// GEMM 1: qkv. BM=128, BN=256, BK=64, 512 thr (8 waves, 2M x 4N). R9: ds_read
// <-> MFMA software pipeline. Per-pipe arithmetic (R8 post-mortem): LDS reads
// 1536 cy/K-tile/CU vs MFMA 1242 cy were SERIALIZED by the read->barrier->MFMA
// phase structure. New schedule overlaps them: ph0 reads bf_hi(kt) then MFMA
// j0-1 (af x bf_lo, read last iter); mid-tile s_waitcnt vmcnt(3) lgkmcnt(0) +
// ONE s_barrier (publishes slot kt+1, drains all ds_reads = cross-wave stage
// fence); ph1 reads af/bf_lo of slot kt+1 then MFMA j2-3 (af x bf_hi).
// Ledger: stage into slot (kt+2)%3 at kt-ph0 is safe -- the only reads of
// that slot (bf_hi of kt-1) drained at mid-(kt-1) before its barrier.
// ---------------------------------------------------------------------------
__global__ __launch_bounds__(512, 2) void gemm_qkv_mfma(
    const ushort* __restrict__ A, const ushort* __restrict__ Bt,
    const float* __restrict__ bias, ushort* __restrict__ q,
    ushort* __restrict__ k, ushort* __restrict__ v) {
  __shared__ __align__(16) ushort KA[3][128 * 64];
  __shared__ __align__(16) ushort KB[3][256 * 64];
  const int wave = threadIdx.x >> 6, lane = threadIdx.x & 63;
  const int c = lane & 15, quad = lane >> 4;
  const int wm = wave >> 2, wn = wave & 3;
  const int bid0 = blockIdx.x;
  const int bid = (bid0 & 7) * 96 + (bid0 >> 3);  // XCD chunking, bijective
  const int m0 = (bid / 12) << 7;
  const int n0 = (bid % 12) << 8;

  int aRow[2], aX[2], bRow[4], bX[4];
#pragma unroll
  for (int p = 0; p < 2; ++p) {
    const int flat = p * 8192 + (int)threadIdx.x * 16;
    aRow[p] = flat >> 7;
    aX[p] = (((flat & 127) >> 4) ^ (aRow[p] & 7)) * 8;
  }
#pragma unroll
  for (int p = 0; p < 4; ++p) {
    const int flat = p * 8192 + (int)threadIdx.x * 16;
    bRow[p] = flat >> 7;
    bX[p] = (((flat & 127) >> 4) ^ (bRow[p] & 7)) * 8;
  }
  int fOffA[2][4], fOffB[2][4];
#pragma unroll
  for (int ko = 0; ko < 2; ++ko) {
#pragma unroll
    for (int i = 0; i < 4; ++i)
      fOffA[ko][i] = swz_frag64(wm * 64 + i * 16 + c, quad, ko);
#pragma unroll
    for (int j = 0; j < 4; ++j)
      fOffB[ko][j] = swz_frag64(wn * 64 + j * 16 + c, quad, ko);
  }

  f32x4 acc[4][4];
#pragma unroll
  for (int i = 0; i < 4; ++i)
#pragma unroll
    for (int j = 0; j < 4; ++j) acc[i][j] = (f32x4){0.f, 0.f, 0.f, 0.f};

  // prologue: stage kt=0 -> slot0, kt=1 -> slot1 (6 loads each)
#pragma unroll
  for (int p = 0; p < 4; ++p)
    GL2LDS16(Bt + (size_t)(n0 + bRow[p]) * C_ + bX[p],
             (char*)KB[0] + p * 8192 + wave * 1024);
#pragma unroll
  for (int p = 0; p < 2; ++p)
    GL2LDS16(A + (size_t)(m0 + aRow[p]) * C_ + aX[p],
             (char*)KA[0] + p * 8192 + wave * 1024);
#pragma unroll
  for (int p = 0; p < 4; ++p)
    GL2LDS16(Bt + (size_t)(n0 + bRow[p]) * C_ + 64 + bX[p],
             (char*)KB[1] + p * 8192 + wave * 1024);
#pragma unroll
  for (int p = 0; p < 2; ++p)
    GL2LDS16(A + (size_t)(m0 + aRow[p]) * C_ + 64 + aX[p],
             (char*)KA[1] + p * 8192 + wave * 1024);
  asm volatile("s_waitcnt vmcnt(6)" ::: "memory");
  __builtin_amdgcn_s_barrier();

  // pre-read kt=0's af + bf_lo from slot 0
  short8 af[4][2], bfA[2][2], bfB[2][2];
  {
    const char* la0 = (const char*)KA[0];
    const char* lb0 = (const char*)KB[0];
#pragma unroll
    for (int i = 0; i < 4; ++i)
#pragma unroll
      for (int ko = 0; ko < 2; ++ko)
        af[i][ko] = *(const short8*)(la0 + fOffA[ko][i]);
#pragma unroll
    for (int d = 0; d < 2; ++d)
#pragma unroll
      for (int ko = 0; ko < 2; ++ko)
        bfA[d][ko] = *(const short8*)(lb0 + fOffB[ko][d]);
  }

  int cur = 0;
  for (int kt = 0; kt < 16; ++kt) {
    const int nxt = (cur == 2) ? 0 : cur + 1;
    const int s2 = (nxt == 2) ? 0 : nxt + 1;
    const char* lb = (const char*)KB[cur];
    const int kk2 = (kt + 2) << 6;
    const bool more = (kt + 2) < 16;

    // ---- phase 0: read bf_hi(kt); stage B0,B1,A0 -> s2; MFMA j0-1 ----
#pragma unroll
    for (int d = 0; d < 2; ++d)
#pragma unroll
      for (int ko = 0; ko < 2; ++ko)
        bfB[d][ko] = *(const short8*)(lb + fOffB[ko][2 + d]);
    if (more) {
      GL2LDS16(Bt + (size_t)(n0 + bRow[0]) * C_ + kk2 + bX[0],
               (char*)KB[s2] + 0 * 8192 + wave * 1024);
      GL2LDS16(Bt + (size_t)(n0 + bRow[1]) * C_ + kk2 + bX[1],
               (char*)KB[s2] + 1 * 8192 + wave * 1024);
      GL2LDS16(A + (size_t)(m0 + aRow[0]) * C_ + kk2 + aX[0],
               (char*)KA[s2] + 0 * 8192 + wave * 1024);
    }
    __builtin_amdgcn_s_setprio(1);
#pragma unroll
    for (int i = 0; i < 4; ++i)
#pragma unroll
      for (int dj = 0; dj < 2; ++dj)
#pragma unroll
        for (int ko = 0; ko < 2; ++ko)
          acc[i][dj] = __builtin_amdgcn_mfma_f32_16x16x32_bf16(
              af[i][ko], bfA[dj][ko], acc[i][dj], 0, 0, 0);
    __builtin_amdgcn_s_setprio(0);

    // ---- mid-tile: drain ds_reads (cross-wave stage fence) + publish nxt --
    if (more)
      asm volatile("s_waitcnt vmcnt(3) lgkmcnt(0)" ::: "memory");
    else
      asm volatile("s_waitcnt vmcnt(0) lgkmcnt(0)" ::: "memory");
    __builtin_amdgcn_s_barrier();

    // ---- phase 1: read af/bf_lo of slot nxt; stage B2,B3,A1; MFMA j2-3 ----
    short8 afN[4][2], bfAN[2][2];
    if (kt + 1 < 16) {
      const char* lan = (const char*)KA[nxt];
      const char* lbn = (const char*)KB[nxt];
#pragma unroll
      for (int i = 0; i < 4; ++i)
#pragma unroll
        for (int ko = 0; ko < 2; ++ko)
          afN[i][ko] = *(const short8*)(lan + fOffA[ko][i]);
#pragma unroll
      for (int d = 0; d < 2; ++d)
#pragma unroll
        for (int ko = 0; ko < 2; ++ko)
          bfAN[d][ko] = *(const short8*)(lbn + fOffB[ko][d]);
    }
    if (more) {
      GL2LDS16(Bt + (size_t)(n0 + bRow[2]) * C_ + kk2 + bX[2],
               (char*)KB[s2] + 2 * 8192 + wave * 1024);
      GL2LDS16(Bt + (size_t)(n0 + bRow[3]) * C_ + kk2 + bX[3],
               (char*)KB[s2] + 3 * 8192 + wave * 1024);
      GL2LDS16(A + (size_t)(m0 + aRow[1]) * C_ + kk2 + aX[1],
               (char*)KA[s2] + 1 * 8192 + wave * 1024);
    }
    __builtin_amdgcn_s_setprio(1);
#pragma unroll
    for (int i = 0; i < 4; ++i)
#pragma unroll
      for (int dj = 0; dj < 2; ++dj)
#pragma unroll
        for (int ko = 0; ko < 2; ++ko)
          acc[i][2 + dj] = __builtin_amdgcn_mfma_f32_16x16x32_bf16(
              af[i][ko], bfB[dj][ko], acc[i][2 + dj], 0, 0, 0);
    __builtin_amdgcn_s_setprio(0);
    if (kt + 1 < 16) {
#pragma unroll
      for (int i = 0; i < 4; ++i)
#pragma unroll
        for (int ko = 0; ko < 2; ++ko) af[i][ko] = afN[i][ko];
#pragma unroll
      for (int d = 0; d < 2; ++d)
#pragma unroll
        for (int ko = 0; ko < 2; ++ko) bfA[d][ko] = bfAN[d][ko];
    }
    cur = nxt;
  }

  const int s = n0 >> 10;  // uniform per block (BN=256 divides 1024)
  if (s == 2) {
    // v epilogue: [B,H,D,T], reg r spans 4 consecutive t -> ushort4
#pragma unroll
    for (int j = 0; j < 4; ++j) {
      const int n = n0 + wn * 64 + j * 16 + c;
      const int h = (n >> 6) & 15, d = n & 63;
      const float bval = bias[n];
#pragma unroll
      for (int i = 0; i < 4; ++i) {
        const int m = m0 + wm * 64 + i * 16 + quad * 4;
        const int b = m >> 11, t = m & 2047;
        ushort4 pk = {f2bf(acc[i][j][0] + bval), f2bf(acc[i][j][1] + bval),
                      f2bf(acc[i][j][2] + bval), f2bf(acc[i][j][3] + bval)};
        *(ushort4*)(v + (((size_t)((b << 4) + h) << 6) + d) * T_ + t) = pk;
      }
    }
  } else {
    ushort* outp = (s == 0) ? q : k;
    const float sc = (s == 0) ? QSCALE : 1.0f;
#pragma unroll
    for (int j = 0; j < 4; ++j) {
      const int n = n0 + wn * 64 + j * 16 + c;
      const int h = (n >> 6) & 15, d = n & 63;
      const float bval = bias[n];
#pragma unroll
      for (int i = 0; i < 4; ++i) {
#pragma unroll
        for (int r = 0; r < 4; ++r) {
          const int m = m0 + wm * 64 + i * 16 + quad * 4 + r;
          const int b = m >> 11, t = m & 2047;
          outp[(((size_t)((b << 4) + h) << 11) + t) * 64 + d] =
              f2bf((acc[i][j][r] + bval) * sc);
        }
      }
    }
  }
}

// ---------------------------------------------------------------------------
// GEMM 2 v2: out = y2 @ Wproj + bproj (fp32 out). attn-v8 pattern: async
// double-buffered staging, ONE __syncthreads per K-tile, stage-in-flight
// across the whole compute phase. LDS 64 KB -> 2 blocks/CU. Grid (8, 64).
// ---------------------------------------------------------------------------
__global__ __launch_bounds__(256) void gemm_proj_mfma(
    const ushort* __restrict__ A, const ushort* __restrict__ Bt,
    const float* __restrict__ bias, float* __restrict__ out) {
  __shared__ __align__(16) ushort As[2][128 * 64];
  __shared__ __align__(16) ushort Bs[2][128 * 64];
  const int tid = threadIdx.x;
  const int wave = tid >> 6, lane = tid & 63;
  const int c = lane & 15, quad = lane >> 4;
  const int wm = wave & 1, wn = wave >> 1;
  const int bid0 = blockIdx.y * 8 + blockIdx.x;
  const int bid = (bid0 & 7) * 64 + (bid0 >> 3);  // XCD chunking, bijective
  const int m0 = (bid >> 3) << 7;
  const int n0 = (bid & 7) << 7;

  int sRow[4], sOff[4];
#pragma unroll
  for (int p = 0; p < 4; ++p) swz_src64(wave, lane, p, sRow[p], sOff[p]);
  int fOffA[2][4], fOffB[2][4];
#pragma unroll
  for (int ko = 0; ko < 2; ++ko) {
#pragma unroll
    for (int i = 0; i < 4; ++i)
      fOffA[ko][i] = swz_frag64(wm * 64 + i * 16 + c, quad, ko);
#pragma unroll
    for (int j = 0; j < 4; ++j)
      fOffB[ko][j] = swz_frag64(wn * 64 + j * 16 + c, quad, ko);
  }

  f32x4 acc[4][4];
#pragma unroll
  for (int i = 0; i < 4; ++i)
#pragma unroll
    for (int j = 0; j < 4; ++j) acc[i][j] = (f32x4){0.f, 0.f, 0.f, 0.f};

#define PROJ_STAGE(buf, kk)                                            \
  do {                                                                 \
    _Pragma("unroll") for (int p = 0; p < 4; ++p) {                    \
      GL2LDS16(A + (size_t)(m0 + sRow[p]) * C_ + (kk) + sOff[p],       \
               (char*)As[buf] + p * 4096 + wave * 1024);               \
      GL2LDS16(Bt + (size_t)(n0 + sRow[p]) * C_ + (kk) + sOff[p],      \
               (char*)Bs[buf] + p * 4096 + wave * 1024);               \
    }                                                                  \
  } while (0)

  PROJ_STAGE(0, 0);
  int cur = 0;
  for (int k0 = 0; k0 < C_; k0 += 64) {
    __syncthreads();  // drains vmcnt -> buf[cur] visible to all waves
    if (k0 + 64 < C_) PROJ_STAGE(cur ^ 1, k0 + 64);  // in flight over compute
#pragma unroll
    for (int ko = 0; ko < 2; ++ko) {
      short8 af[4], bf[4];
#pragma unroll
      for (int i = 0; i < 4; ++i)
        af[i] = *(const short8*)((const char*)As[cur] + fOffA[ko][i]);
#pragma unroll
      for (int j = 0; j < 4; ++j)
        bf[j] = *(const short8*)((const char*)Bs[cur] + fOffB[ko][j]);
      __builtin_amdgcn_s_setprio(1);
#pragma unroll
      for (int i = 0; i < 4; ++i)
#pragma unroll
        for (int j = 0; j < 4; ++j)
          acc[i][j] = __builtin_amdgcn_mfma_f32_16x16x32_bf16(af[i], bf[j],
                                                              acc[i][j], 0, 0, 0);
      __builtin_amdgcn_s_setprio(0);
    }
    cur ^= 1;
  }
#undef PROJ_STAGE

#pragma unroll
  for (int j = 0; j < 4; ++j) {
    const int n = n0 + wn * 64 + j * 16 + c;
    const float bval = bias[n];
#pragma unroll
    for (int i = 0; i < 4; ++i) {
#pragma unroll
      for (int r = 0; r < 4; ++r) {
        const int m = m0 + wm * 64 + i * 16 + quad * 4 + r;
        out[(size_t)m * C_ + n] = acc[i][j][r] + bval;
      }
    }
  }
}

// ---------------------------------------------------------------------------
// Flash attention v9: async double-buffered K/V staging + P^T repack via
// register shuffles (no Ps LDS round-trip). LDS 32 KB -> 4-5 blocks/CU.
// ---------------------------------------------------------------------------
__global__ __launch_bounds__(256) void attn(const ushort* __restrict__ q,
                                            const ushort* __restrict__ k,
                                            const ushort* __restrict__ v,
                                            ushort* __restrict__ y2) {
  const int qt = 15 - (int)(blockIdx.x >> 6);  // long tiles first
  const int bh = blockIdx.x & 63;
  const int t0 = qt << 7;
  const int w = threadIdx.x >> 6;
  const int lane = threadIdx.x & 63;
  const int c = lane & 15;
  const int quad = lane >> 4;

  const ushort* qp = q + (size_t)bh * T_ * D_;
  const ushort* kp = k + (size_t)bh * T_ * D_;
  const ushort* vp = v + (size_t)bh * D_ * T_;  // [d][t]

  __shared__ __align__(16) ushort Ks[2][64 * 64];  // [key][d], swizzled rows
  __shared__ __align__(16) ushort Vs[2][64 * 64];  // [d][key], swizzled rows

  short8 qf[2][2];
#pragma unroll
  for (int g = 0; g < 2; ++g) {
    const ushort* qrow = qp + (size_t)(t0 + 32 * w + 16 * g + c) * D_;
    qf[g][0] = *(const short8*)(qrow + quad * 8);
    qf[g][1] = *(const short8*)(qrow + 32 + quad * 8);
  }

  int sRow[2], sX[2];
#pragma unroll
  for (int p = 0; p < 2; ++p) {
    const int flat = p * 4096 + (int)threadIdx.x * 16;
    sRow[p] = flat >> 7;
    sX[p] = (((flat & 127) >> 4) ^ (sRow[p] & 7)) * 8;  // ushort offset
  }

#define STAGE(buf, s0s)                                                   \
  do {                                                                    \
    _Pragma("unroll") for (int p = 0; p < 2; ++p) {                       \
      GL2LDS16(kp + (size_t)((s0s) + sRow[p]) * D_ + sX[p],               \
               (char*)Ks[buf] + p * 4096 + w * 1024);                     \
      GL2LDS16(vp + (size_t)sRow[p] * T_ + (s0s) + sX[p],                 \
               (char*)Vs[buf] + p * 4096 + w * 1024);                     \
    }                                                                     \
  } while (0)

  f32x4 o[2][4];
  float l_i[2] = {0.f, 0.f};
#pragma unroll
  for (int g = 0; g < 2; ++g)
#pragma unroll
    for (int dt = 0; dt < 4; ++dt) o[g][dt] = (f32x4){0.f, 0.f, 0.f, 0.f};

  const int nb = 2 * qt + 2;
  STAGE(0, 0);  // prologue: tile 0 in flight
  int cur = 0;
  const int sA = c + ((quad & 1) << 5);  // shuffle source lanes (i = 0,1)
  const int sB = sA + 16;                // (i = 2,3)

  for (int ib = 0; ib < nb; ++ib) {
    const int s0 = ib << 6;
    // compiler drains vmcnt+lgkmcnt before s_barrier -> buf[cur] visible
    __syncthreads();
    if (ib + 1 < nb) STAGE(cur ^ 1, s0 + 64);  // in flight across compute

    // ---- S^T = K Q^T, K-frags read once, shared across both q-tiles ----
    f32x4 st[2][4];
    __builtin_amdgcn_s_setprio(1);
#pragma unroll
    for (int kt = 0; kt < 4; ++kt) {
      const char* kb = (const char*)Ks[cur];
      short8 af0 = *(const short8*)(kb + swz_frag64(kt * 16 + c, quad, 0));
      short8 af1 = *(const short8*)(kb + swz_frag64(kt * 16 + c, quad, 1));
#pragma unroll
      for (int g = 0; g < 2; ++g) {
        f32x4 a = (f32x4){0.f, 0.f, 0.f, 0.f};
        a = __builtin_amdgcn_mfma_f32_16x16x32_bf16(af0, qf[g][0], a, 0, 0, 0);
        a = __builtin_amdgcn_mfma_f32_16x16x32_bf16(af1, qf[g][1], a, 0, 0, 0);
        st[g][kt] = a;
      }
    }
    __builtin_amdgcn_s_setprio(0);

    // ---- softmax: mask + exp2 + packed bf16 (kept in registers) ----
    unsigned pw[2][4][2];  // [g][kt][b]
#pragma unroll
    for (int g = 0; g < 2; ++g) {
      const int qbase = t0 + 32 * w + 16 * g;
      if (s0 + 63 > qbase) {  // causal mask for this (wave, g)
#pragma unroll
        for (int kt = 0; kt < 4; ++kt)
#pragma unroll
          for (int r = 0; r < 4; ++r)
            if (s0 + kt * 16 + 4 * quad + r > qbase + c) st[g][kt][r] = -1e30f;
      }
      float lacc = 0.f;
#pragma unroll
      for (int kt = 0; kt < 4; ++kt) {
        float p0 = fast_exp2(st[g][kt][0]);
        float p1 = fast_exp2(st[g][kt][1]);
        float p2 = fast_exp2(st[g][kt][2]);
        float p3 = fast_exp2(st[g][kt][3]);
        lacc += (p0 + p1) + (p2 + p3);
        pw[g][kt][0] = cvt_pk_bf16(p0, p1);
        pw[g][kt][1] = cvt_pk_bf16(p2, p3);
      }
      l_i[g] += lacc;
    }

    // ---- P^T repack via shuffles (replaces Ps LDS round-trip) ----
    short8 pf[2][2];
#pragma unroll
    for (int g = 0; g < 2; ++g) {
#pragma unroll
      for (int half = 0; half < 2; ++half) {
        const unsigned lo0 = pw[g][half * 2][0], lo1 = pw[g][half * 2][1];
        const unsigned hi0 = pw[g][half * 2 + 1][0], hi1 = pw[g][half * 2 + 1][1];
        const unsigned a0 = (unsigned)__shfl((int)lo0, sA);
        const unsigned b0 = (unsigned)__shfl((int)hi0, sA);
        const unsigned a1 = (unsigned)__shfl((int)lo1, sA);
        const unsigned b1 = (unsigned)__shfl((int)hi1, sA);
        const unsigned a2 = (unsigned)__shfl((int)lo0, sB);
        const unsigned b2 = (unsigned)__shfl((int)hi0, sB);
        const unsigned a3 = (unsigned)__shfl((int)lo1, sB);
        const unsigned b3 = (unsigned)__shfl((int)hi1, sB);
        uint4 r;
        r.x = (quad & 2) ? b0 : a0;
        r.y = (quad & 2) ? b1 : a1;
        r.z = (quad & 2) ? b2 : a2;
        r.w = (quad & 2) ? b3 : a3;
        pf[g][half] = *(short8*)&r;
      }
    }

    // ---- O^T += V^T P^T (V-frags shared across both q-tiles) ----
    __builtin_amdgcn_s_setprio(1);
#pragma unroll
    for (int dt = 0; dt < 4; ++dt) {
      const char* vb = (const char*)Vs[cur];
      short8 vf0 = *(const short8*)(vb + swz_frag64(dt * 16 + c, quad, 0));
      short8 vf1 = *(const short8*)(vb + swz_frag64(dt * 16 + c, quad, 1));
#pragma unroll
      for (int g = 0; g < 2; ++g) {
        o[g][dt] =
            __builtin_amdgcn_mfma_f32_16x16x32_bf16(vf0, pf[g][0], o[g][dt], 0, 0, 0);
        o[g][dt] =
            __builtin_amdgcn_mfma_f32_16x16x32_bf16(vf1, pf[g][1], o[g][dt], 0, 0, 0);
      }
    }
    __builtin_amdgcn_s_setprio(0);
    cur ^= 1;
  }
#undef STAGE

  float linv[2];
#pragma unroll
  for (int g = 0; g < 2; ++g) {
    float ls = l_i[g];
    ls += __shfl_xor(ls, 16);
    ls += __shfl_xor(ls, 32);
    linv[g] = 1.0f / ls;
  }

  const int b = bh >> 4, h = bh & 15;
#pragma unroll
  for (int g = 0; g < 2; ++g) {
    const int row = t0 + 32 * w + 16 * g + c;
    ushort* dst = y2 + (size_t)(b * T_ + row) * C_ + h * 64;
#pragma unroll
    for (int dt = 0; dt < 4; ++dt) {
      uint2 ov = {cvt_pk_bf16(o[g][dt][0] * linv[g], o[g][dt][1] * linv[g]),
                  cvt_pk_bf16(o[g][dt][2] * linv[g], o[g][dt][3] * linv[g])};
      *(uint2*)(dst + dt * 16 + 4 * quad) = ov;
    }
  }
}

// ---------------------------------------------------------------------------
extern "C" void kernel_launch(void* const* d_in, const int* in_sizes, int n_in,
                              void* d_out, int out_size, void* d_ws,
                              size_t ws_size, hipStream_t stream) {
  const float* x = (const float*)d_in[0];
  const float* Wqkv = (const float*)d_in[1];
  const float* bqkv = (const float*)d_in[2];
  const float* Wproj = (const float*)d_in[3];
  const float* bproj = (const float*)d_in[4];
  float* out = (float*)d_out;

  const size_t per = (size_t)B_ * H_ * T_ * D_;  // 8388608
  ushort* q = (ushort*)d_ws;
  ushort* k = q + per;
  ushort* v = k + per;  // [B,H,D,T]
  ushort* y2 = v + per;
  ushort* xb = y2 + per;
  ushort* Wqkvt = xb + per;              // [3072][1024]
  ushort* Wprojt = Wqkvt + 3 * C_ * C_;  // [1024][1024]

  prepass<<<dim3(12288), 256, 0, stream>>>(x, Wqkv, Wproj, xb, Wqkvt, Wprojt);
  gemm_qkv_mfma<<<dim3(768), 512, 0, stream>>>(xb, Wqkvt, bqkv, q, k, v);
  attn<<<dim3(1024), 256, 0, stream>>>(q, k, v, y2);
  gemm_proj_mfma<<<dim3(8, 64), 256, 0, stream>>>(y2, Wprojt, bproj, out);
}

// Round 10
// 238.217 us; speedup vs baseline: 1.0866x; 1.0314x over previous
//
#include <hip/hip_runtime.h>
#include <hip/hip_bf16.h>

#define B_ 4
#define T_ 2048
#define C_ 1024
#define H_ 16
#define D_ 64

typedef __attribute__((ext_vector_type(8))) short short8;
typedef __attribute__((ext_vector_type(4))) float f32x4;

// q pre-scale: (1/sqrt(D)) * log2(e) so attn uses raw v_exp_f32 (exp2)
#define QSCALE 0.18033688011112042f

static __device__ __forceinline__ unsigned short f2bf(float f) {
  unsigned u = __float_as_uint(f);
  u += 0x7fff + ((u >> 16) & 1);  // round-to-nearest-even
  return (unsigned short)(u >> 16);
}

// packed bf16 convert: dword = {bf16(lo), bf16(hi)<<16}, RNE (T12 primitive)
static __device__ __forceinline__ unsigned cvt_pk_bf16(float lo, float hi) {
  unsigned r;
  asm("v_cvt_pk_bf16_f32 %0, %1, %2" : "=v"(r) : "v"(lo), "v"(hi));
  return r;
}

static __device__ __forceinline__ float fast_exp2(float x) {
#if __has_builtin(__builtin_amdgcn_exp2f)
  return __builtin_amdgcn_exp2f(x);
#else
  return exp2f(x);
#endif
}

#define GL2LDS16(g, l)                                              \
  __builtin_amdgcn_global_load_lds(                                 \
      (const __attribute__((address_space(1))) void*)(g),           \
      (__attribute__((address_space(3))) void*)(l), 16, 0, 0)

// ---------------------------------------------------------------------------
// Fused pre-pass: x->bf16 (blocks 0..8191), Wqkv transpose (8192..11263),
// Wproj transpose (11264..12287). At HBM roofline (~120 MB moved).
// ---------------------------------------------------------------------------
__global__ __launch_bounds__(256) void prepass(
    const float* __restrict__ x, const float* __restrict__ Wq,
    const float* __restrict__ Wp, ushort* __restrict__ xb,
    ushort* __restrict__ Wqt, ushort* __restrict__ Wpt) {
  __shared__ ushort tile[32][33];
  const int bid = blockIdx.x;
  if (bid < 8192) {
    const size_t i = ((size_t)bid * 256 + threadIdx.x) * 4;
    float4 vv = *(const float4*)(x + i);
    ushort4 o = {f2bf(vv.x), f2bf(vv.y), f2bf(vv.z), f2bf(vv.w)};
    *(ushort4*)(xb + i) = o;
    return;
  }
  const float* in;
  ushort* out;
  int N, tix;
  if (bid < 8192 + 3072) {
    in = Wq; out = Wqt; N = 3 * C_; tix = bid - 8192;
  } else {
    in = Wp; out = Wpt; N = C_; tix = bid - 11264;
  }
  const int nT = N >> 5;
  const int k0 = (tix / nT) << 5, n0 = (tix % nT) << 5;
  const int r = threadIdx.x >> 3;
  const int c4 = (threadIdx.x & 7) << 2;
  float4 v = *(const float4*)(in + (size_t)(k0 + r) * N + n0 + c4);
  tile[c4 + 0][r] = f2bf(v.x);
  tile[c4 + 1][r] = f2bf(v.y);
  tile[c4 + 2][r] = f2bf(v.z);
  tile[c4 + 3][r] = f2bf(v.w);
  __syncthreads();
  ushort4 o = {tile[r][c4], tile[r][c4 + 1], tile[r][c4 + 2], tile[r][c4 + 3]};
  *(ushort4*)(out + (size_t)(n0 + r) * C_ + k0 + c4) = o;
}

// ---------------------------------------------------------------------------
// LDS XOR-swizzle for 128 B rows: chunk (16 B) at position pos of row r holds
// global chunk pos ^ (r & 7). Staging pre-swizzles the SOURCE address.
// ---------------------------------------------------------------------------
static __device__ __forceinline__ void swz_src64(int wave, int lane, int p,
                                                 int& row, int& offU) {
  const int flat = p * 4096 + wave * 1024 + lane * 16;  // byte offset in tile
  row = flat >> 7;                    // 128 B per row
  const int pos = (flat & 127) >> 4;  // chunk index in row
  const int x = pos ^ (row & 7);
  offU = x * 8;  // element offset within the row's span
}
static __device__ __forceinline__ int swz_frag64(int r, int quad, int ko) {
  return r * 128 + (((quad | (ko << 2)) ^ (r & 7)) << 4);  // bytes
}

// ---------------------------------------------------------------------------
// GEMM 1: qkv (R9 structure, kept). Session finding: time == (FETCH+WRITE)/
// ~1.8 TB/s for ALL schedule variants (134 MB -> ~74 us). FETCH is near-
// compulsory: 33.5 MB A (L2-resident/XCD) + 48 MB B (6 MB x 8 XCDs, doesn't
// fit L2 beside A) + 50 MB write. Schedule is not the binding constraint.
// ---------------------------------------------------------------------------
__global__ __launch_bounds__(512, 2) void gemm_qkv_mfma(
    const ushort* __restrict__ A, const ushort* __restrict__ Bt,
    const float* __restrict__ bias, ushort* __restrict__ q,
    ushort* __restrict__ k, ushort* __restrict__ v) {
  __shared__ __align__(16) ushort KA[3][128 * 64];
  __shared__ __align__(16) ushort KB[3][256 * 64];
  const int wave = threadIdx.x >> 6, lane = threadIdx.x & 63;
  const int c = lane & 15, quad = lane >> 4;
  const int wm = wave >> 2, wn = wave & 3;
  const int bid0 = blockIdx.x;
  const int bid = (bid0 & 7) * 96 + (bid0 >> 3);  // XCD chunking, bijective
  const int m0 = (bid / 12) << 7;
  const int n0 = (bid % 12) << 8;

  int aRow[2], aX[2], bRow[4], bX[4];
#pragma unroll
  for (int p = 0; p < 2; ++p) {
    const int flat = p * 8192 + (int)threadIdx.x * 16;
    aRow[p] = flat >> 7;
    aX[p] = (((flat & 127) >> 4) ^ (aRow[p] & 7)) * 8;
  }
#pragma unroll
  for (int p = 0; p < 4; ++p) {
    const int flat = p * 8192 + (int)threadIdx.x * 16;
    bRow[p] = flat >> 7;
    bX[p] = (((flat & 127) >> 4) ^ (bRow[p] & 7)) * 8;
  }
  int fOffA[2][4], fOffB[2][4];
#pragma unroll
  for (int ko = 0; ko < 2; ++ko) {
#pragma unroll
    for (int i = 0; i < 4; ++i)
      fOffA[ko][i] = swz_frag64(wm * 64 + i * 16 + c, quad, ko);
#pragma unroll
    for (int j = 0; j < 4; ++j)
      fOffB[ko][j] = swz_frag64(wn * 64 + j * 16 + c, quad, ko);
  }

  f32x4 acc[4][4];
#pragma unroll
  for (int i = 0; i < 4; ++i)
#pragma unroll
    for (int j = 0; j < 4; ++j) acc[i][j] = (f32x4){0.f, 0.f, 0.f, 0.f};

  // prologue: stage kt=0 -> slot0, kt=1 -> slot1 (6 loads each)
#pragma unroll
  for (int p = 0; p < 4; ++p)
    GL2LDS16(Bt + (size_t)(n0 + bRow[p]) * C_ + bX[p],
             (char*)KB[0] + p * 8192 + wave * 1024);
#pragma unroll
  for (int p = 0; p < 2; ++p)
    GL2LDS16(A + (size_t)(m0 + aRow[p]) * C_ + aX[p],
             (char*)KA[0] + p * 8192 + wave * 1024);
#pragma unroll
  for (int p = 0; p < 4; ++p)
    GL2LDS16(Bt + (size_t)(n0 + bRow[p]) * C_ + 64 + bX[p],
             (char*)KB[1] + p * 8192 + wave * 1024);
#pragma unroll
  for (int p = 0; p < 2; ++p)
    GL2LDS16(A + (size_t)(m0 + aRow[p]) * C_ + 64 + aX[p],
             (char*)KA[1] + p * 8192 + wave * 1024);
  asm volatile("s_waitcnt vmcnt(6)" ::: "memory");
  __builtin_amdgcn_s_barrier();

  // pre-read kt=0's af + bf_lo from slot 0
  short8 af[4][2], bfA[2][2], bfB[2][2];
  {
    const char* la0 = (const char*)KA[0];
    const char* lb0 = (const char*)KB[0];
#pragma unroll
    for (int i = 0; i < 4; ++i)
#pragma unroll
      for (int ko = 0; ko < 2; ++ko)
        af[i][ko] = *(const short8*)(la0 + fOffA[ko][i]);
#pragma unroll
    for (int d = 0; d < 2; ++d)
#pragma unroll
      for (int ko = 0; ko < 2; ++ko)
        bfA[d][ko] = *(const short8*)(lb0 + fOffB[ko][d]);
  }

  int cur = 0;
  for (int kt = 0; kt < 16; ++kt) {
    const int nxt = (cur == 2) ? 0 : cur + 1;
    const int s2 = (nxt == 2) ? 0 : nxt + 1;
    const char* lb = (const char*)KB[cur];
    const int kk2 = (kt + 2) << 6;
    const bool more = (kt + 2) < 16;

    // ---- phase 0: read bf_hi(kt); stage B0,B1,A0 -> s2; MFMA j0-1 ----
#pragma unroll
    for (int d = 0; d < 2; ++d)
#pragma unroll
      for (int ko = 0; ko < 2; ++ko)
        bfB[d][ko] = *(const short8*)(lb + fOffB[ko][2 + d]);
    if (more) {
      GL2LDS16(Bt + (size_t)(n0 + bRow[0]) * C_ + kk2 + bX[0],
               (char*)KB[s2] + 0 * 8192 + wave * 1024);
      GL2LDS16(Bt + (size_t)(n0 + bRow[1]) * C_ + kk2 + bX[1],
               (char*)KB[s2] + 1 * 8192 + wave * 1024);
      GL2LDS16(A + (size_t)(m0 + aRow[0]) * C_ + kk2 + aX[0],
               (char*)KA[s2] + 0 * 8192 + wave * 1024);
    }
    __builtin_amdgcn_s_setprio(1);
#pragma unroll
    for (int i = 0; i < 4; ++i)
#pragma unroll
      for (int dj = 0; dj < 2; ++dj)
#pragma unroll
        for (int ko = 0; ko < 2; ++ko)
          acc[i][dj] = __builtin_amdgcn_mfma_f32_16x16x32_bf16(
              af[i][ko], bfA[dj][ko], acc[i][dj], 0, 0, 0);
    __builtin_amdgcn_s_setprio(0);

    // ---- mid-tile: drain ds_reads (cross-wave stage fence) + publish nxt --
    if (more)
      asm volatile("s_waitcnt vmcnt(3) lgkmcnt(0)" ::: "memory");
    else
      asm volatile("s_waitcnt vmcnt(0) lgkmcnt(0)" ::: "memory");
    __builtin_amdgcn_s_barrier();

    // ---- phase 1: read af/bf_lo of slot nxt; stage B2,B3,A1; MFMA j2-3 ----
    short8 afN[4][2], bfAN[2][2];
    if (kt + 1 < 16) {
      const char* lan = (const char*)KA[nxt];
      const char* lbn = (const char*)KB[nxt];
#pragma unroll
      for (int i = 0; i < 4; ++i)
#pragma unroll
        for (int ko = 0; ko < 2; ++ko)
          afN[i][ko] = *(const short8*)(lan + fOffA[ko][i]);
#pragma unroll
      for (int d = 0; d < 2; ++d)
#pragma unroll
        for (int ko = 0; ko < 2; ++ko)
          bfAN[d][ko] = *(const short8*)(lbn + fOffB[ko][d]);
    }
    if (more) {
      GL2LDS16(Bt + (size_t)(n0 + bRow[2]) * C_ + kk2 + bX[2],
               (char*)KB[s2] + 2 * 8192 + wave * 1024);
      GL2LDS16(Bt + (size_t)(n0 + bRow[3]) * C_ + kk2 + bX[3],
               (char*)KB[s2] + 3 * 8192 + wave * 1024);
      GL2LDS16(A + (size_t)(m0 + aRow[1]) * C_ + kk2 + aX[1],
               (char*)KA[s2] + 1 * 8192 + wave * 1024);
    }
    __builtin_amdgcn_s_setprio(1);
#pragma unroll
    for (int i = 0; i < 4; ++i)
#pragma unroll
      for (int dj = 0; dj < 2; ++dj)
#pragma unroll
        for (int ko = 0; ko < 2; ++ko)
          acc[i][2 + dj] = __builtin_amdgcn_mfma_f32_16x16x32_bf16(
              af[i][ko], bfB[dj][ko], acc[i][2 + dj], 0, 0, 0);
    __builtin_amdgcn_s_setprio(0);
    if (kt + 1 < 16) {
#pragma unroll
      for (int i = 0; i < 4; ++i)
#pragma unroll
        for (int ko = 0; ko < 2; ++ko) af[i][ko] = afN[i][ko];
#pragma unroll
      for (int d = 0; d < 2; ++d)
#pragma unroll
        for (int ko = 0; ko < 2; ++ko) bfA[d][ko] = bfAN[d][ko];
    }
    cur = nxt;
  }

  const int s = n0 >> 10;  // uniform per block (BN=256 divides 1024)
  if (s == 2) {
    // v epilogue: [B,H,D,T], reg r spans 4 consecutive t -> ushort4
#pragma unroll
    for (int j = 0; j < 4; ++j) {
      const int n = n0 + wn * 64 + j * 16 + c;
      const int h = (n >> 6) & 15, d = n & 63;
      const float bval = bias[n];
#pragma unroll
      for (int i = 0; i < 4; ++i) {
        const int m = m0 + wm * 64 + i * 16 + quad * 4;
        const int b = m >> 11, t = m & 2047;
        ushort4 pk = {f2bf(acc[i][j][0] + bval), f2bf(acc[i][j][1] + bval),
                      f2bf(acc[i][j][2] + bval), f2bf(acc[i][j][3] + bval)};
        *(ushort4*)(v + (((size_t)((b << 4) + h) << 6) + d) * T_ + t) = pk;
      }
    }
  } else {
    ushort* outp = (s == 0) ? q : k;
    const float sc = (s == 0) ? QSCALE : 1.0f;
#pragma unroll
    for (int j = 0; j < 4; ++j) {
      const int n = n0 + wn * 64 + j * 16 + c;
      const int h = (n >> 6) & 15, d = n & 63;
      const float bval = bias[n];
#pragma unroll
      for (int i = 0; i < 4; ++i) {
#pragma unroll
        for (int r = 0; r < 4; ++r) {
          const int m = m0 + wm * 64 + i * 16 + quad * 4 + r;
          const int b = m >> 11, t = m & 2047;
          outp[(((size_t)((b << 4) + h) << 11) + t) * 64 + d] =
              f2bf((acc[i][j][r] + bval) * sc);
        }
      }
    }
  }
}

// ---------------------------------------------------------------------------
// GEMM 2 v2: out = y2 @ Wproj + bproj (fp32 out). attn-v8 pattern: async
// double-buffered staging, ONE __syncthreads per K-tile, stage-in-flight
// across the whole compute phase. LDS 64 KB -> 2 blocks/CU. Grid (8, 64).
// ---------------------------------------------------------------------------
__global__ __launch_bounds__(256) void gemm_proj_mfma(
    const ushort* __restrict__ A, const ushort* __restrict__ Bt,
    const float* __restrict__ bias, float* __restrict__ out) {
  __shared__ __align__(16) ushort As[2][128 * 64];
  __shared__ __align__(16) ushort Bs[2][128 * 64];
  const int tid = threadIdx.x;
  const int wave = tid >> 6, lane = tid & 63;
  const int c = lane & 15, quad = lane >> 4;
  const int wm = wave & 1, wn = wave >> 1;
  const int bid0 = blockIdx.y * 8 + blockIdx.x;
  const int bid = (bid0 & 7) * 64 + (bid0 >> 3);  // XCD chunking, bijective
  const int m0 = (bid >> 3) << 7;
  const int n0 = (bid & 7) << 7;

  int sRow[4], sOff[4];
#pragma unroll
  for (int p = 0; p < 4; ++p) swz_src64(wave, lane, p, sRow[p], sOff[p]);
  int fOffA[2][4], fOffB[2][4];
#pragma unroll
  for (int ko = 0; ko < 2; ++ko) {
#pragma unroll
    for (int i = 0; i < 4; ++i)
      fOffA[ko][i] = swz_frag64(wm * 64 + i * 16 + c, quad, ko);
#pragma unroll
    for (int j = 0; j < 4; ++j)
      fOffB[ko][j] = swz_frag64(wn * 64 + j * 16 + c, quad, ko);
  }

  f32x4 acc[4][4];
#pragma unroll
  for (int i = 0; i < 4; ++i)
#pragma unroll
    for (int j = 0; j < 4; ++j) acc[i][j] = (f32x4){0.f, 0.f, 0.f, 0.f};

#define PROJ_STAGE(buf, kk)                                            \
  do {                                                                 \
    _Pragma("unroll") for (int p = 0; p < 4; ++p) {                    \
      GL2LDS16(A + (size_t)(m0 + sRow[p]) * C_ + (kk) + sOff[p],       \
               (char*)As[buf] + p * 4096 + wave * 1024);               \
      GL2LDS16(Bt + (size_t)(n0 + sRow[p]) * C_ + (kk) + sOff[p],      \
               (char*)Bs[buf] + p * 4096 + wave * 1024);               \
    }                                                                  \
  } while (0)

  PROJ_STAGE(0, 0);
  int cur = 0;
  for (int k0 = 0; k0 < C_; k0 += 64) {
    __syncthreads();  // drains vmcnt -> buf[cur] visible to all waves
    if (k0 + 64 < C_) PROJ_STAGE(cur ^ 1, k0 + 64);  // in flight over compute
#pragma unroll
    for (int ko = 0; ko < 2; ++ko) {
      short8 af[4], bf[4];
#pragma unroll
      for (int i = 0; i < 4; ++i)
        af[i] = *(const short8*)((const char*)As[cur] + fOffA[ko][i]);
#pragma unroll
      for (int j = 0; j < 4; ++j)
        bf[j] = *(const short8*)((const char*)Bs[cur] + fOffB[ko][j]);
      __builtin_amdgcn_s_setprio(1);
#pragma unroll
      for (int i = 0; i < 4; ++i)
#pragma unroll
        for (int j = 0; j < 4; ++j)
          acc[i][j] = __builtin_amdgcn_mfma_f32_16x16x32_bf16(af[i], bf[j],
                                                              acc[i][j], 0, 0, 0);
      __builtin_amdgcn_s_setprio(0);
    }
    cur ^= 1;
  }
#undef PROJ_STAGE

#pragma unroll
  for (int j = 0; j < 4; ++j) {
    const int n = n0 + wn * 64 + j * 16 + c;
    const float bval = bias[n];
#pragma unroll
    for (int i = 0; i < 4; ++i) {
#pragma unroll
      for (int r = 0; r < 4; ++r) {
        const int m = m0 + wm * 64 + i * 16 + quad * 4 + r;
        out[(size_t)m * C_ + n] = acc[i][j][r] + bval;
      }
    }
  }
}

// ---------------------------------------------------------------------------
// Flash attention v8 (reverted from v9): async double-buffered K/V staging +
// Ps LDS round-trip for the P^T repack. v9's shuffle repack regressed: __shfl
// = ds_bpermute (same LDS pipe, 4.5M conflicts) AND dropping Ps shrank LDS to
// 32 KB -> exactly 4 blocks/CU -> NO hardware backfill queue (the R4 drain).
// v8's 50.4 KB -> 3 blocks/CU = 768 resident + 256 queued: queue backfills
// the causal drain (long-qt dispatched first). Session-proven best attn.
// ---------------------------------------------------------------------------
__global__ __launch_bounds__(256) void attn(const ushort* __restrict__ q,
                                            const ushort* __restrict__ k,
                                            const ushort* __restrict__ v,
                                            ushort* __restrict__ y2) {
  const int qt = 15 - (int)(blockIdx.x >> 6);  // long tiles first
  const int bh = blockIdx.x & 63;
  const int t0 = qt << 7;
  const int w = threadIdx.x >> 6;
  const int lane = threadIdx.x & 63;
  const int c = lane & 15;
  const int quad = lane >> 4;

  const ushort* qp = q + (size_t)bh * T_ * D_;
  const ushort* kp = k + (size_t)bh * T_ * D_;
  const ushort* vp = v + (size_t)bh * D_ * T_;  // [d][t]

  __shared__ __align__(16) ushort Ks[2][64 * 64];  // [key][d], swizzled rows
  __shared__ __align__(16) ushort Vs[2][64 * 64];  // [d][key], swizzled rows
  __shared__ __align__(16) ushort Ps[4][32][72];   // per-wave [query][key]

  short8 qf[2][2];
#pragma unroll
  for (int g = 0; g < 2; ++g) {
    const ushort* qrow = qp + (size_t)(t0 + 32 * w + 16 * g + c) * D_;
    qf[g][0] = *(const short8*)(qrow + quad * 8);
    qf[g][1] = *(const short8*)(qrow + 32 + quad * 8);
  }

  int sRow[2], sX[2];
#pragma unroll
  for (int p = 0; p < 2; ++p) {
    const int flat = p * 4096 + (int)threadIdx.x * 16;
    sRow[p] = flat >> 7;
    sX[p] = (((flat & 127) >> 4) ^ (sRow[p] & 7)) * 8;  // ushort offset
  }

#define STAGE(buf, s0s)                                                   \
  do {                                                                    \
    _Pragma("unroll") for (int p = 0; p < 2; ++p) {                       \
      GL2LDS16(kp + (size_t)((s0s) + sRow[p]) * D_ + sX[p],               \
               (char*)Ks[buf] + p * 4096 + w * 1024);                     \
      GL2LDS16(vp + (size_t)sRow[p] * T_ + (s0s) + sX[p],                 \
               (char*)Vs[buf] + p * 4096 + w * 1024);                     \
    }                                                                     \
  } while (0)

  f32x4 o[2][4];
  float l_i[2] = {0.f, 0.f};
#pragma unroll
  for (int g = 0; g < 2; ++g)
#pragma unroll
    for (int dt = 0; dt < 4; ++dt) o[g][dt] = (f32x4){0.f, 0.f, 0.f, 0.f};

  const int nb = 2 * qt + 2;
  STAGE(0, 0);  // prologue: tile 0 in flight
  int cur = 0;

  for (int ib = 0; ib < nb; ++ib) {
    const int s0 = ib << 6;
    // compiler drains vmcnt+lgkmcnt before s_barrier -> buf[cur] visible
    __syncthreads();
    if (ib + 1 < nb) STAGE(cur ^ 1, s0 + 64);  // in flight across compute

    // ---- S^T = K Q^T, K-frags read once, shared across both q-tiles ----
    f32x4 st[2][4];
    __builtin_amdgcn_s_setprio(1);
#pragma unroll
    for (int kt = 0; kt < 4; ++kt) {
      const char* kb = (const char*)Ks[cur];
      short8 af0 = *(const short8*)(kb + swz_frag64(kt * 16 + c, quad, 0));
      short8 af1 = *(const short8*)(kb + swz_frag64(kt * 16 + c, quad, 1));
#pragma unroll
      for (int g = 0; g < 2; ++g) {
        f32x4 a = (f32x4){0.f, 0.f, 0.f, 0.f};
        a = __builtin_amdgcn_mfma_f32_16x16x32_bf16(af0, qf[g][0], a, 0, 0, 0);
        a = __builtin_amdgcn_mfma_f32_16x16x32_bf16(af1, qf[g][1], a, 0, 0, 0);
        st[g][kt] = a;
      }
    }
    __builtin_amdgcn_s_setprio(0);

#pragma unroll
    for (int g = 0; g < 2; ++g) {
      const int qbase = t0 + 32 * w + 16 * g;
      if (s0 + 63 > qbase) {  // causal mask for this (wave, g)
#pragma unroll
        for (int kt = 0; kt < 4; ++kt)
#pragma unroll
          for (int r = 0; r < 4; ++r)
            if (s0 + kt * 16 + 4 * quad + r > qbase + c) st[g][kt][r] = -1e30f;
      }
      float lacc = 0.f;
#pragma unroll
      for (int kt = 0; kt < 4; ++kt) {
        float p0 = fast_exp2(st[g][kt][0]);
        float p1 = fast_exp2(st[g][kt][1]);
        float p2 = fast_exp2(st[g][kt][2]);
        float p3 = fast_exp2(st[g][kt][3]);
        lacc += (p0 + p1) + (p2 + p3);
        uint2 pw = {cvt_pk_bf16(p0, p1), cvt_pk_bf16(p2, p3)};
        *(uint2*)(&Ps[w][g * 16 + c][kt * 16 + 4 * quad]) = pw;
      }
      l_i[g] += lacc;
    }

    // ---- O^T += V^T P^T (V-frags shared across both q-tiles) ----
    short8 pf[2][2];
#pragma unroll
    for (int g = 0; g < 2; ++g) {
      pf[g][0] = *(const short8*)(&Ps[w][g * 16 + c][quad * 8]);
      pf[g][1] = *(const short8*)(&Ps[w][g * 16 + c][32 + quad * 8]);
    }
    __builtin_amdgcn_s_setprio(1);
#pragma unroll
    for (int dt = 0; dt < 4; ++dt) {
      const char* vb = (const char*)Vs[cur];
      short8 vf0 = *(const short8*)(vb + swz_frag64(dt * 16 + c, quad, 0));
      short8 vf1 = *(const short8*)(vb + swz_frag64(dt * 16 + c, quad, 1));
#pragma unroll
      for (int g = 0; g < 2; ++g) {
        o[g][dt] =
            __builtin_amdgcn_mfma_f32_16x16x32_bf16(vf0, pf[g][0], o[g][dt], 0, 0, 0);
        o[g][dt] =
            __builtin_amdgcn_mfma_f32_16x16x32_bf16(vf1, pf[g][1], o[g][dt], 0, 0, 0);
      }
    }
    __builtin_amdgcn_s_setprio(0);
    cur ^= 1;
  }
#undef STAGE

  float linv[2];
#pragma unroll
  for (int g = 0; g < 2; ++g) {
    float ls = l_i[g];
    ls += __shfl_xor(ls, 16);
    ls += __shfl_xor(ls, 32);
    linv[g] = 1.0f / ls;
  }

  const int b = bh >> 4, h = bh & 15;
#pragma unroll
  for (int g = 0; g < 2; ++g) {
    const int row = t0 + 32 * w + 16 * g + c;
    ushort* dst = y2 + (size_t)(b * T_ + row) * C_ + h * 64;
#pragma unroll
    for (int dt = 0; dt < 4; ++dt) {
      uint2 ov = {cvt_pk_bf16(o[g][dt][0] * linv[g], o[g][dt][1] * linv[g]),
                  cvt_pk_bf16(o[g][dt][2] * linv[g], o[g][dt][3] * linv[g])};
      *(uint2*)(dst + dt * 16 + 4 * quad) = ov;
    }
  }
}

// ---------------------------------------------------------------------------
extern "C" void kernel_launch(void* const* d_in, const int* in_sizes, int n_in,
                              void* d_out, int out_size, void* d_ws,
                              size_t ws_size, hipStream_t stream) {
  const float* x = (const float*)d_in[0];
  const float* Wqkv = (const float*)d_in[1];
  const float* bqkv = (const float*)d_in[2];
  const float* Wproj = (const float*)d_in[3];
  const float* bproj = (const float*)d_in[4];
  float* out = (float*)d_out;

  const size_t per = (size_t)B_ * H_ * T_ * D_;  // 8388608
  ushort* q = (ushort*)d_ws;
  ushort* k = q + per;
  ushort* v = k + per;  // [B,H,D,T]
  ushort* y2 = v + per;
  ushort* xb = y2 + per;
  ushort* Wqkvt = xb + per;              // [3072][1024]
  ushort* Wprojt = Wqkvt + 3 * C_ * C_;  // [1024][1024]

  prepass<<<dim3(12288), 256, 0, stream>>>(x, Wqkv, Wproj, xb, Wqkvt, Wprojt);
  gemm_qkv_mfma<<<dim3(768), 512, 0, stream>>>(xb, Wqkvt, bqkv, q, k, v);
  attn<<<dim3(1024), 256, 0, stream>>>(q, k, v, y2);
  gemm_proj_mfma<<<dim3(8, 64), 256, 0, stream>>>(y2, Wprojt, bproj, out);
}

// Round 11
// 236.531 us; speedup vs baseline: 1.0943x; 1.0071x over previous
//
#include <hip/hip_runtime.h>
#include <hip/hip_bf16.h>

#define B_ 4
#define T_ 2048
#define C_ 1024
#define H_ 16
#define D_ 64

typedef __attribute__((ext_vector_type(8))) short short8;
typedef __attribute__((ext_vector_type(4))) float f32x4;

// q pre-scale: (1/sqrt(D)) * log2(e) so attn uses raw v_exp_f32 (exp2)
#define QSCALE 0.18033688011112042f

static __device__ __forceinline__ unsigned short f2bf(float f) {
  unsigned u = __float_as_uint(f);
  u += 0x7fff + ((u >> 16) & 1);  // round-to-nearest-even
  return (unsigned short)(u >> 16);
}

// packed bf16 convert: dword = {bf16(lo), bf16(hi)<<16}, RNE (T12 primitive)
static __device__ __forceinline__ unsigned cvt_pk_bf16(float lo, float hi) {
  unsigned r;
  asm("v_cvt_pk_bf16_f32 %0, %1, %2" : "=v"(r) : "v"(lo), "v"(hi));
  return r;
}

static __device__ __forceinline__ float fast_exp2(float x) {
#if __has_builtin(__builtin_amdgcn_exp2f)
  return __builtin_amdgcn_exp2f(x);
#else
  return exp2f(x);
#endif
}

#define GL2LDS16(g, l)                                              \
  __builtin_amdgcn_global_load_lds(                                 \
      (const __attribute__((address_space(1))) void*)(g),           \
      (__attribute__((address_space(3))) void*)(l), 16, 0, 0)

// ---------------------------------------------------------------------------
// Fused pre-pass: x->bf16 (blocks 0..8191), Wqkv transpose (8192..11263),
// Wproj transpose (11264..12287). At HBM roofline (~120 MB moved).
// ---------------------------------------------------------------------------
__global__ __launch_bounds__(256) void prepass(
    const float* __restrict__ x, const float* __restrict__ Wq,
    const float* __restrict__ Wp, ushort* __restrict__ xb,
    ushort* __restrict__ Wqt, ushort* __restrict__ Wpt) {
  __shared__ ushort tile[32][33];
  const int bid = blockIdx.x;
  if (bid < 8192) {
    const size_t i = ((size_t)bid * 256 + threadIdx.x) * 4;
    float4 vv = *(const float4*)(x + i);
    ushort4 o = {f2bf(vv.x), f2bf(vv.y), f2bf(vv.z), f2bf(vv.w)};
    *(ushort4*)(xb + i) = o;
    return;
  }
  const float* in;
  ushort* out;
  int N, tix;
  if (bid < 8192 + 3072) {
    in = Wq; out = Wqt; N = 3 * C_; tix = bid - 8192;
  } else {
    in = Wp; out = Wpt; N = C_; tix = bid - 11264;
  }
  const int nT = N >> 5;
  const int k0 = (tix / nT) << 5, n0 = (tix % nT) << 5;
  const int r = threadIdx.x >> 3;
  const int c4 = (threadIdx.x & 7) << 2;
  float4 v = *(const float4*)(in + (size_t)(k0 + r) * N + n0 + c4);
  tile[c4 + 0][r] = f2bf(v.x);
  tile[c4 + 1][r] = f2bf(v.y);
  tile[c4 + 2][r] = f2bf(v.z);
  tile[c4 + 3][r] = f2bf(v.w);
  __syncthreads();
  ushort4 o = {tile[r][c4], tile[r][c4 + 1], tile[r][c4 + 2], tile[r][c4 + 3]};
  *(ushort4*)(out + (size_t)(n0 + r) * C_ + k0 + c4) = o;
}

// ---------------------------------------------------------------------------
// LDS XOR-swizzle for 128 B rows: chunk (16 B) at position pos of row r holds
// global chunk pos ^ (r & 7). Staging pre-swizzles the SOURCE address.
// ---------------------------------------------------------------------------
static __device__ __forceinline__ void swz_src64(int wave, int lane, int p,
                                                 int& row, int& offU) {
  const int flat = p * 4096 + wave * 1024 + lane * 16;  // byte offset in tile
  row = flat >> 7;                    // 128 B per row
  const int pos = (flat & 127) >> 4;  // chunk index in row
  const int x = pos ^ (row & 7);
  offU = x * 8;  // element offset within the row's span
}
static __device__ __forceinline__ int swz_frag64(int r, int quad, int ko) {
  return r * 128 + (((quad | (ko << 2)) ^ (r & 7)) << 4);  // bytes
}

// ---------------------------------------------------------------------------
// GEMM 1: qkv (R9 structure, kept). Session finding: time == (FETCH+WRITE)/
// ~1.8 TB/s for ALL schedule variants (134 MB -> ~74 us). FETCH is near-
// compulsory: 33.5 MB A (L2-resident/XCD) + 48 MB B (6 MB x 8 XCDs, doesn't
// fit L2 beside A) + 50 MB write. Schedule is not the binding constraint.
// ---------------------------------------------------------------------------
__global__ __launch_bounds__(512, 2) void gemm_qkv_mfma(
    const ushort* __restrict__ A, const ushort* __restrict__ Bt,
    const float* __restrict__ bias, ushort* __restrict__ q,
    ushort* __restrict__ k, ushort* __restrict__ v) {
  __shared__ __align__(16) ushort KA[3][128 * 64];
  __shared__ __align__(16) ushort KB[3][256 * 64];
  const int wave = threadIdx.x >> 6, lane = threadIdx.x & 63;
  const int c = lane & 15, quad = lane >> 4;
  const int wm = wave >> 2, wn = wave & 3;
  const int bid0 = blockIdx.x;
  const int bid = (bid0 & 7) * 96 + (bid0 >> 3);  // XCD chunking, bijective
  const int m0 = (bid / 12) << 7;
  const int n0 = (bid % 12) << 8;

  int aRow[2], aX[2], bRow[4], bX[4];
#pragma unroll
  for (int p = 0; p < 2; ++p) {
    const int flat = p * 8192 + (int)threadIdx.x * 16;
    aRow[p] = flat >> 7;
    aX[p] = (((flat & 127) >> 4) ^ (aRow[p] & 7)) * 8;
  }
#pragma unroll
  for (int p = 0; p < 4; ++p) {
    const int flat = p * 8192 + (int)threadIdx.x * 16;
    bRow[p] = flat >> 7;
    bX[p] = (((flat & 127) >> 4) ^ (bRow[p] & 7)) * 8;
  }
  int fOffA[2][4], fOffB[2][4];
#pragma unroll
  for (int ko = 0; ko < 2; ++ko) {
#pragma unroll
    for (int i = 0; i < 4; ++i)
      fOffA[ko][i] = swz_frag64(wm * 64 + i * 16 + c, quad, ko);
#pragma unroll
    for (int j = 0; j < 4; ++j)
      fOffB[ko][j] = swz_frag64(wn * 64 + j * 16 + c, quad, ko);
  }

  f32x4 acc[4][4];
#pragma unroll
  for (int i = 0; i < 4; ++i)
#pragma unroll
    for (int j = 0; j < 4; ++j) acc[i][j] = (f32x4){0.f, 0.f, 0.f, 0.f};

  // prologue: stage kt=0 -> slot0, kt=1 -> slot1 (6 loads each)
#pragma unroll
  for (int p = 0; p < 4; ++p)
    GL2LDS16(Bt + (size_t)(n0 + bRow[p]) * C_ + bX[p],
             (char*)KB[0] + p * 8192 + wave * 1024);
#pragma unroll
  for (int p = 0; p < 2; ++p)
    GL2LDS16(A + (size_t)(m0 + aRow[p]) * C_ + aX[p],
             (char*)KA[0] + p * 8192 + wave * 1024);
#pragma unroll
  for (int p = 0; p < 4; ++p)
    GL2LDS16(Bt + (size_t)(n0 + bRow[p]) * C_ + 64 + bX[p],
             (char*)KB[1] + p * 8192 + wave * 1024);
#pragma unroll
  for (int p = 0; p < 2; ++p)
    GL2LDS16(A + (size_t)(m0 + aRow[p]) * C_ + 64 + aX[p],
             (char*)KA[1] + p * 8192 + wave * 1024);
  asm volatile("s_waitcnt vmcnt(6)" ::: "memory");
  __builtin_amdgcn_s_barrier();

  // pre-read kt=0's af + bf_lo from slot 0
  short8 af[4][2], bfA[2][2], bfB[2][2];
  {
    const char* la0 = (const char*)KA[0];
    const char* lb0 = (const char*)KB[0];
#pragma unroll
    for (int i = 0; i < 4; ++i)
#pragma unroll
      for (int ko = 0; ko < 2; ++ko)
        af[i][ko] = *(const short8*)(la0 + fOffA[ko][i]);
#pragma unroll
    for (int d = 0; d < 2; ++d)
#pragma unroll
      for (int ko = 0; ko < 2; ++ko)
        bfA[d][ko] = *(const short8*)(lb0 + fOffB[ko][d]);
  }

  int cur = 0;
  for (int kt = 0; kt < 16; ++kt) {
    const int nxt = (cur == 2) ? 0 : cur + 1;
    const int s2 = (nxt == 2) ? 0 : nxt + 1;
    const char* lb = (const char*)KB[cur];
    const int kk2 = (kt + 2) << 6;
    const bool more = (kt + 2) < 16;

    // ---- phase 0: read bf_hi(kt); stage B0,B1,A0 -> s2; MFMA j0-1 ----
#pragma unroll
    for (int d = 0; d < 2; ++d)
#pragma unroll
      for (int ko = 0; ko < 2; ++ko)
        bfB[d][ko] = *(const short8*)(lb + fOffB[ko][2 + d]);
    if (more) {
      GL2LDS16(Bt + (size_t)(n0 + bRow[0]) * C_ + kk2 + bX[0],
               (char*)KB[s2] + 0 * 8192 + wave * 1024);
      GL2LDS16(Bt + (size_t)(n0 + bRow[1]) * C_ + kk2 + bX[1],
               (char*)KB[s2] + 1 * 8192 + wave * 1024);
      GL2LDS16(A + (size_t)(m0 + aRow[0]) * C_ + kk2 + aX[0],
               (char*)KA[s2] + 0 * 8192 + wave * 1024);
    }
    __builtin_amdgcn_s_setprio(1);
#pragma unroll
    for (int i = 0; i < 4; ++i)
#pragma unroll
      for (int dj = 0; dj < 2; ++dj)
#pragma unroll
        for (int ko = 0; ko < 2; ++ko)
          acc[i][dj] = __builtin_amdgcn_mfma_f32_16x16x32_bf16(
              af[i][ko], bfA[dj][ko], acc[i][dj], 0, 0, 0);
    __builtin_amdgcn_s_setprio(0);

    // ---- mid-tile: drain ds_reads (cross-wave stage fence) + publish nxt --
    if (more)
      asm volatile("s_waitcnt vmcnt(3) lgkmcnt(0)" ::: "memory");
    else
      asm volatile("s_waitcnt vmcnt(0) lgkmcnt(0)" ::: "memory");
    __builtin_amdgcn_s_barrier();

    // ---- phase 1: read af/bf_lo of slot nxt; stage B2,B3,A1; MFMA j2-3 ----
    short8 afN[4][2], bfAN[2][2];
    if (kt + 1 < 16) {
      const char* lan = (const char*)KA[nxt];
      const char* lbn = (const char*)KB[nxt];
#pragma unroll
      for (int i = 0; i < 4; ++i)
#pragma unroll
        for (int ko = 0; ko < 2; ++ko)
          afN[i][ko] = *(const short8*)(lan + fOffA[ko][i]);
#pragma unroll
      for (int d = 0; d < 2; ++d)
#pragma unroll
        for (int ko = 0; ko < 2; ++ko)
          bfAN[d][ko] = *(const short8*)(lbn + fOffB[ko][d]);
    }
    if (more) {
      GL2LDS16(Bt + (size_t)(n0 + bRow[2]) * C_ + kk2 + bX[2],
               (char*)KB[s2] + 2 * 8192 + wave * 1024);
      GL2LDS16(Bt + (size_t)(n0 + bRow[3]) * C_ + kk2 + bX[3],
               (char*)KB[s2] + 3 * 8192 + wave * 1024);
      GL2LDS16(A + (size_t)(m0 + aRow[1]) * C_ + kk2 + aX[1],
               (char*)KA[s2] + 1 * 8192 + wave * 1024);
    }
    __builtin_amdgcn_s_setprio(1);
#pragma unroll
    for (int i = 0; i < 4; ++i)
#pragma unroll
      for (int dj = 0; dj < 2; ++dj)
#pragma unroll
        for (int ko = 0; ko < 2; ++ko)
          acc[i][2 + dj] = __builtin_amdgcn_mfma_f32_16x16x32_bf16(
              af[i][ko], bfB[dj][ko], acc[i][2 + dj], 0, 0, 0);
    __builtin_amdgcn_s_setprio(0);
    if (kt + 1 < 16) {
#pragma unroll
      for (int i = 0; i < 4; ++i)
#pragma unroll
        for (int ko = 0; ko < 2; ++ko) af[i][ko] = afN[i][ko];
#pragma unroll
      for (int d = 0; d < 2; ++d)
#pragma unroll
        for (int ko = 0; ko < 2; ++ko) bfA[d][ko] = bfAN[d][ko];
    }
    cur = nxt;
  }

  const int s = n0 >> 10;  // uniform per block (BN=256 divides 1024)
  if (s == 2) {
    // v epilogue: [B,H,D,T], reg r spans 4 consecutive t -> ushort4
#pragma unroll
    for (int j = 0; j < 4; ++j) {
      const int n = n0 + wn * 64 + j * 16 + c;
      const int h = (n >> 6) & 15, d = n & 63;
      const float bval = bias[n];
#pragma unroll
      for (int i = 0; i < 4; ++i) {
        const int m = m0 + wm * 64 + i * 16 + quad * 4;
        const int b = m >> 11, t = m & 2047;
        ushort4 pk = {f2bf(acc[i][j][0] + bval), f2bf(acc[i][j][1] + bval),
                      f2bf(acc[i][j][2] + bval), f2bf(acc[i][j][3] + bval)};
        *(ushort4*)(v + (((size_t)((b << 4) + h) << 6) + d) * T_ + t) = pk;
      }
    }
  } else {
    ushort* outp = (s == 0) ? q : k;
    const float sc = (s == 0) ? QSCALE : 1.0f;
#pragma unroll
    for (int j = 0; j < 4; ++j) {
      const int n = n0 + wn * 64 + j * 16 + c;
      const int h = (n >> 6) & 15, d = n & 63;
      const float bval = bias[n];
#pragma unroll
      for (int i = 0; i < 4; ++i) {
#pragma unroll
        for (int r = 0; r < 4; ++r) {
          const int m = m0 + wm * 64 + i * 16 + quad * 4 + r;
          const int b = m >> 11, t = m & 2047;
          outp[(((size_t)((b << 4) + h) << 11) + t) * 64 + d] =
              f2bf((acc[i][j][r] + bval) * sc);
        }
      }
    }
  }
}

// ---------------------------------------------------------------------------
// GEMM 2 v2: out = y2 @ Wproj + bproj (fp32 out). attn-v8 pattern: async
// double-buffered staging, ONE __syncthreads per K-tile, stage-in-flight
// across the whole compute phase. LDS 64 KB -> 2 blocks/CU. Grid (8, 64).
// ---------------------------------------------------------------------------
__global__ __launch_bounds__(256) void gemm_proj_mfma(
    const ushort* __restrict__ A, const ushort* __restrict__ Bt,
    const float* __restrict__ bias, float* __restrict__ out) {
  __shared__ __align__(16) ushort As[2][128 * 64];
  __shared__ __align__(16) ushort Bs[2][128 * 64];
  const int tid = threadIdx.x;
  const int wave = tid >> 6, lane = tid & 63;
  const int c = lane & 15, quad = lane >> 4;
  const int wm = wave & 1, wn = wave >> 1;
  const int bid0 = blockIdx.y * 8 + blockIdx.x;
  const int bid = (bid0 & 7) * 64 + (bid0 >> 3);  // XCD chunking, bijective
  const int m0 = (bid >> 3) << 7;
  const int n0 = (bid & 7) << 7;

  int sRow[4], sOff[4];
#pragma unroll
  for (int p = 0; p < 4; ++p) swz_src64(wave, lane, p, sRow[p], sOff[p]);
  int fOffA[2][4], fOffB[2][4];
#pragma unroll
  for (int ko = 0; ko < 2; ++ko) {
#pragma unroll
    for (int i = 0; i < 4; ++i)
      fOffA[ko][i] = swz_frag64(wm * 64 + i * 16 + c, quad, ko);
#pragma unroll
    for (int j = 0; j < 4; ++j)
      fOffB[ko][j] = swz_frag64(wn * 64 + j * 16 + c, quad, ko);
  }

  f32x4 acc[4][4];
#pragma unroll
  for (int i = 0; i < 4; ++i)
#pragma unroll
    for (int j = 0; j < 4; ++j) acc[i][j] = (f32x4){0.f, 0.f, 0.f, 0.f};

#define PROJ_STAGE(buf, kk)                                            \
  do {                                                                 \
    _Pragma("unroll") for (int p = 0; p < 4; ++p) {                    \
      GL2LDS16(A + (size_t)(m0 + sRow[p]) * C_ + (kk) + sOff[p],       \
               (char*)As[buf] + p * 4096 + wave * 1024);               \
      GL2LDS16(Bt + (size_t)(n0 + sRow[p]) * C_ + (kk) + sOff[p],      \
               (char*)Bs[buf] + p * 4096 + wave * 1024);               \
    }                                                                  \
  } while (0)

  PROJ_STAGE(0, 0);
  int cur = 0;
  for (int k0 = 0; k0 < C_; k0 += 64) {
    __syncthreads();  // drains vmcnt -> buf[cur] visible to all waves
    if (k0 + 64 < C_) PROJ_STAGE(cur ^ 1, k0 + 64);  // in flight over compute
#pragma unroll
    for (int ko = 0; ko < 2; ++ko) {
      short8 af[4], bf[4];
#pragma unroll
      for (int i = 0; i < 4; ++i)
        af[i] = *(const short8*)((const char*)As[cur] + fOffA[ko][i]);
#pragma unroll
      for (int j = 0; j < 4; ++j)
        bf[j] = *(const short8*)((const char*)Bs[cur] + fOffB[ko][j]);
      __builtin_amdgcn_s_setprio(1);
#pragma unroll
      for (int i = 0; i < 4; ++i)
#pragma unroll
        for (int j = 0; j < 4; ++j)
          acc[i][j] = __builtin_amdgcn_mfma_f32_16x16x32_bf16(af[i], bf[j],
                                                              acc[i][j], 0, 0, 0);
      __builtin_amdgcn_s_setprio(0);
    }
    cur ^= 1;
  }
#undef PROJ_STAGE

#pragma unroll
  for (int j = 0; j < 4; ++j) {
    const int n = n0 + wn * 64 + j * 16 + c;
    const float bval = bias[n];
#pragma unroll
    for (int i = 0; i < 4; ++i) {
#pragma unroll
      for (int r = 0; r < 4; ++r) {
        const int m = m0 + wm * 64 + i * 16 + quad * 4 + r;
        out[(size_t)m * C_ + n] = acc[i][j][r] + bval;
      }
    }
  }
}

// ---------------------------------------------------------------------------
// Flash attention v10: QBLK=64. Makespan analysis (R10 post-mortem): with
// QBLK=128 the drain is bounded by the LONGEST item (qt=15: 32 units) vs
// mean slot load 22.7 -> 71% utilization cap, matching measured occupancy.
// Halving the q-tile halves the longest item (16 old-units), grid 2048 =
// 768 resident (3/CU) + 1280-deep backfill queue, and finer causal
// granularity trims ~3% masked waste. Cost: K/V-frag reads no longer
// amortized over 2 q-groups per wave (est +15%/unit). Wave handles 16
// queries; structure otherwise identical to v8 (async dbuf staging, Ps
// round-trip, setprio).
// ---------------------------------------------------------------------------
__global__ __launch_bounds__(256) void attn(const ushort* __restrict__ q,
                                            const ushort* __restrict__ k,
                                            const ushort* __restrict__ v,
                                            ushort* __restrict__ y2) {
  const int qt = 31 - (int)(blockIdx.x >> 6);  // 0..31, long tiles first
  const int bh = blockIdx.x & 63;
  const int t0 = qt << 6;  // 64 queries per block
  const int w = threadIdx.x >> 6;
  const int lane = threadIdx.x & 63;
  const int c = lane & 15;
  const int quad = lane >> 4;

  const ushort* qp = q + (size_t)bh * T_ * D_;
  const ushort* kp = k + (size_t)bh * T_ * D_;
  const ushort* vp = v + (size_t)bh * D_ * T_;  // [d][t]

  __shared__ __align__(16) ushort Ks[2][64 * 64];  // [key][d], swizzled rows
  __shared__ __align__(16) ushort Vs[2][64 * 64];  // [d][key], swizzled rows
  __shared__ __align__(16) ushort Ps[4][16][72];   // per-wave [query][key]

  short8 qf[2];
  {
    const ushort* qrow = qp + (size_t)(t0 + 16 * w + c) * D_;
    qf[0] = *(const short8*)(qrow + quad * 8);
    qf[1] = *(const short8*)(qrow + 32 + quad * 8);
  }

  int sRow[2], sX[2];
#pragma unroll
  for (int p = 0; p < 2; ++p) {
    const int flat = p * 4096 + (int)threadIdx.x * 16;
    sRow[p] = flat >> 7;
    sX[p] = (((flat & 127) >> 4) ^ (sRow[p] & 7)) * 8;  // ushort offset
  }

#define STAGE(buf, s0s)                                                   \
  do {                                                                    \
    _Pragma("unroll") for (int p = 0; p < 2; ++p) {                       \
      GL2LDS16(kp + (size_t)((s0s) + sRow[p]) * D_ + sX[p],               \
               (char*)Ks[buf] + p * 4096 + w * 1024);                     \
      GL2LDS16(vp + (size_t)sRow[p] * T_ + (s0s) + sX[p],                 \
               (char*)Vs[buf] + p * 4096 + w * 1024);                     \
    }                                                                     \
  } while (0)

  f32x4 o[4];
  float l_i = 0.f;
#pragma unroll
  for (int dt = 0; dt < 4; ++dt) o[dt] = (f32x4){0.f, 0.f, 0.f, 0.f};

  const int nb = qt + 1;
  STAGE(0, 0);  // prologue: tile 0 in flight
  int cur = 0;

  for (int ib = 0; ib < nb; ++ib) {
    const int s0 = ib << 6;
    // compiler drains vmcnt+lgkmcnt before s_barrier -> buf[cur] visible
    __syncthreads();
    if (ib + 1 < nb) STAGE(cur ^ 1, s0 + 64);  // in flight across compute

    // ---- S^T = K Q^T ----
    f32x4 st[4];
    __builtin_amdgcn_s_setprio(1);
#pragma unroll
    for (int kt = 0; kt < 4; ++kt) {
      const char* kb = (const char*)Ks[cur];
      short8 af0 = *(const short8*)(kb + swz_frag64(kt * 16 + c, quad, 0));
      short8 af1 = *(const short8*)(kb + swz_frag64(kt * 16 + c, quad, 1));
      f32x4 a = (f32x4){0.f, 0.f, 0.f, 0.f};
      a = __builtin_amdgcn_mfma_f32_16x16x32_bf16(af0, qf[0], a, 0, 0, 0);
      a = __builtin_amdgcn_mfma_f32_16x16x32_bf16(af1, qf[1], a, 0, 0, 0);
      st[kt] = a;
    }
    __builtin_amdgcn_s_setprio(0);

    // ---- softmax: mask + exp2 + packed bf16 to Ps ----
    {
      const int qbase = t0 + 16 * w;
      if (s0 + 63 > qbase) {  // causal mask for this wave
#pragma unroll
        for (int kt = 0; kt < 4; ++kt)
#pragma unroll
          for (int r = 0; r < 4; ++r)
            if (s0 + kt * 16 + 4 * quad + r > qbase + c) st[kt][r] = -1e30f;
      }
      float lacc = 0.f;
#pragma unroll
      for (int kt = 0; kt < 4; ++kt) {
        float p0 = fast_exp2(st[kt][0]);
        float p1 = fast_exp2(st[kt][1]);
        float p2 = fast_exp2(st[kt][2]);
        float p3 = fast_exp2(st[kt][3]);
        lacc += (p0 + p1) + (p2 + p3);
        uint2 pw = {cvt_pk_bf16(p0, p1), cvt_pk_bf16(p2, p3)};
        *(uint2*)(&Ps[w][c][kt * 16 + 4 * quad]) = pw;
      }
      l_i += lacc;
    }

    // ---- O^T += V^T P^T ----
    short8 pf[2];
    pf[0] = *(const short8*)(&Ps[w][c][quad * 8]);
    pf[1] = *(const short8*)(&Ps[w][c][32 + quad * 8]);
    __builtin_amdgcn_s_setprio(1);
#pragma unroll
    for (int dt = 0; dt < 4; ++dt) {
      const char* vb = (const char*)Vs[cur];
      short8 vf0 = *(const short8*)(vb + swz_frag64(dt * 16 + c, quad, 0));
      short8 vf1 = *(const short8*)(vb + swz_frag64(dt * 16 + c, quad, 1));
      o[dt] = __builtin_amdgcn_mfma_f32_16x16x32_bf16(vf0, pf[0], o[dt], 0, 0, 0);
      o[dt] = __builtin_amdgcn_mfma_f32_16x16x32_bf16(vf1, pf[1], o[dt], 0, 0, 0);
    }
    __builtin_amdgcn_s_setprio(0);
    cur ^= 1;
  }
#undef STAGE

  float linv;
  {
    float ls = l_i;
    ls += __shfl_xor(ls, 16);
    ls += __shfl_xor(ls, 32);
    linv = 1.0f / ls;
  }

  const int b = bh >> 4, h = bh & 15;
  {
    const int row = t0 + 16 * w + c;
    ushort* dst = y2 + (size_t)(b * T_ + row) * C_ + h * 64;
#pragma unroll
    for (int dt = 0; dt < 4; ++dt) {
      uint2 ov = {cvt_pk_bf16(o[dt][0] * linv, o[dt][1] * linv),
                  cvt_pk_bf16(o[dt][2] * linv, o[dt][3] * linv)};
      *(uint2*)(dst + dt * 16 + 4 * quad) = ov;
    }
  }
}

// ---------------------------------------------------------------------------
extern "C" void kernel_launch(void* const* d_in, const int* in_sizes, int n_in,
                              void* d_out, int out_size, void* d_ws,
                              size_t ws_size, hipStream_t stream) {
  const float* x = (const float*)d_in[0];
  const float* Wqkv = (const float*)d_in[1];
  const float* bqkv = (const float*)d_in[2];
  const float* Wproj = (const float*)d_in[3];
  const float* bproj = (const float*)d_in[4];
  float* out = (float*)d_out;

  const size_t per = (size_t)B_ * H_ * T_ * D_;  // 8388608
  ushort* q = (ushort*)d_ws;
  ushort* k = q + per;
  ushort* v = k + per;  // [B,H,D,T]
  ushort* y2 = v + per;
  ushort* xb = y2 + per;
  ushort* Wqkvt = xb + per;              // [3072][1024]
  ushort* Wprojt = Wqkvt + 3 * C_ * C_;  // [1024][1024]

  prepass<<<dim3(12288), 256, 0, stream>>>(x, Wqkv, Wproj, xb, Wqkvt, Wprojt);
  gemm_qkv_mfma<<<dim3(768), 512, 0, stream>>>(xb, Wqkvt, bqkv, q, k, v);
  attn<<<dim3(2048), 256, 0, stream>>>(q, k, v, y2);
  gemm_proj_mfma<<<dim3(8, 64), 256, 0, stream>>>(y2, Wprojt, bproj, out);
}